// Round 4
// baseline (3599.201 us; speedup 1.0000x reference)
//
#include <hip/hip_runtime.h>
#include <hip/hip_fp16.h>

#define EMB 100
#define EMB4 25            // EMB/4 float4s per row (fp32 layouts)
#define SLOTS 13           // 8-half slot bands per row (104 halves padded)
#define N_ITEMS 200000
#define BATCH 100
#define HIST_MAX 50
#define ITEM_ELEMS 20000000  // N_ITEMS * EMB
#define SCAN_B 1024
#define NSCAN_BLOCKS ((N_ITEMS + SCAN_B - 1) / SCAN_B)   // 196 (< 256)
#define GROWS 128          // rows per block in banded gather
#define GCAP 5120          // LDS-cached nnz per block (mean 4096 + slack; overflow -> global)
#define TR 64              // rows per block in transpose/epilogue kernels
#define VALQ 16383.0f      // 14-bit val quantization

typedef unsigned int u32;
typedef u32 u4v __attribute__((ext_vector_type(4)));

// ================= CSR build =================

__global__ void k_histogram(const int* __restrict__ row, int* __restrict__ cnt, int nnz) {
    int i = blockIdx.x * blockDim.x + threadIdx.x;
    if (i < nnz) atomicAdd(&cnt[row[i]], 1);
}

__global__ void k_scan_local(const int* __restrict__ cnt, int* __restrict__ rowptr,
                             int* __restrict__ blocksum, int n) {
    __shared__ int sd[SCAN_B];
    int b = blockIdx.x, tid = threadIdx.x;
    int i = b * SCAN_B + tid;
    int v = (i < n) ? cnt[i] : 0;
    sd[tid] = v;
    __syncthreads();
    for (int off = 1; off < SCAN_B; off <<= 1) {
        int t = (tid >= off) ? sd[tid - off] : 0;
        __syncthreads();
        sd[tid] += t;
        __syncthreads();
    }
    if (i < n) rowptr[i + 1] = sd[tid];
    if (tid == SCAN_B - 1) blocksum[b] = sd[tid];
}

__global__ void k_scan_blocks(int* __restrict__ blocksum, int nb) {
    __shared__ int sd[256];
    int tid = threadIdx.x;
    int v = (tid < nb) ? blocksum[tid] : 0;
    sd[tid] = v;
    __syncthreads();
    for (int off = 1; off < 256; off <<= 1) {
        int t = (tid >= off) ? sd[tid - off] : 0;
        __syncthreads();
        sd[tid] += t;
        __syncthreads();
    }
    if (tid < nb) blocksum[tid] = sd[tid] - v;  // exclusive
}

__global__ void k_scan_add(int* __restrict__ rowptr, const int* __restrict__ blocksum, int n) {
    int i = blockIdx.x * blockDim.x + threadIdx.x;
    if (i == 0) rowptr[0] = 0;
    if (i < n) rowptr[i + 1] += blocksum[i / SCAN_B];
}

// fill CSR; packed entry = (col<<14) | round(val*16383)  (col < 2^18, val in [0,1))
__global__ void k_fill(const int* __restrict__ row, const int* __restrict__ col,
                       const float* __restrict__ val, const int* __restrict__ rowptr,
                       int* __restrict__ cnt, u32* __restrict__ cvp, int nnz) {
    int i = blockIdx.x * blockDim.x + threadIdx.x;
    if (i >= nnz) return;
    int r = row[i];
    int old = atomicSub(&cnt[r], 1);        // old in [1..len]
    int pos = rowptr[r] + old - 1;
    u32 q = (u32)__float2uint_rn(val[i] * VALQ);
    cvp[pos] = ((u32)col[i] << 14) | q;
}

// ================= emb fp32 -> transposed fp16 table [SLOTS][N_ITEMS][8] =================

__global__ void k_to_half_t(const float* __restrict__ src, __half* __restrict__ dst) {
    __shared__ float tile[TR][105];
    int base = blockIdx.x * TR;
    int tid = threadIdx.x;  // 256
    for (int idx = tid; idx < TR * EMB; idx += 256) {
        int rr = idx / EMB, e = idx - rr * EMB;
        int gr = base + rr;
        tile[rr][e] = (gr < N_ITEMS) ? src[(size_t)gr * EMB + e] : 0.f;
    }
    for (int idx = tid; idx < TR * 4; idx += 256)
        tile[idx / 4][EMB + (idx & 3)] = 0.f;
    __syncthreads();
    for (int p = tid; p < SLOTS * TR; p += 256) {
        int s = p / TR, rr = p - s * TR;
        int gr = base + rr;
        if (gr < N_ITEMS) {
            __half h8[8];
#pragma unroll
            for (int k = 0; k < 8; k++) h8[k] = __float2half(tile[rr][s * 8 + k]);
            *(u4v*)(dst + ((size_t)s * N_ITEMS + gr) * 8) = *(const u4v*)h8;
        }
    }
}

// ================= banded gather SpMM =================
// x/out layout: [SLOTS][N_ITEMS][8 halves]. Block = 128 rows, whole grid co-resident,
// loops slot bands in lockstep -> per-instant x working set = 3.2MB -> per-XCD L2 resident.

__device__ __forceinline__ void fma8(float s[8], const uint4& hv, float f) {
    const __half2* hp = reinterpret_cast<const __half2*>(&hv);
#pragma unroll
    for (int k = 0; k < 4; k++) {
        float2 p = __half22float2(hp[k]);
        s[2 * k]     += f * p.x;
        s[2 * k + 1] += f * p.y;
    }
}

__global__ __launch_bounds__(GROWS, 4)
void k_spmm_banded(const int* __restrict__ rowptr, const u32* __restrict__ cvp,
                   const __half* __restrict__ xt, const float* __restrict__ gamma,
                   int gidx, __half* __restrict__ outt) {
    __shared__ int rp[GROWS + 1];
    __shared__ u32 cvs[GCAP];
    int base = blockIdx.x * GROWS;
    int tid = threadIdx.x;
    for (int i = tid; i <= GROWS; i += GROWS) {
        int rr = base + i;
        rp[i] = rowptr[rr < N_ITEMS ? rr : N_ITEMS];
    }
    __syncthreads();
    int gbase = rp[0];
    int nl = rp[GROWS] - gbase;
    if (nl > GCAP) nl = GCAP;
    for (int i = tid; i < nl; i += GROWS) cvs[i] = cvp[gbase + i];
    __syncthreads();

    int r = base + tid;
    bool active = (r < N_ITEMS);
    int a = active ? rp[tid] - gbase : 0;
    int b = active ? rp[tid + 1] - gbase : 0;
    int bl = (b < nl) ? b : nl;          // LDS-covered end
    float g = gamma[gidx];
    const float inv = 1.0f / VALQ;

    for (int s = 0; s < SLOTS; s++) {
        const __half* xs = xt + (size_t)s * N_ITEMS * 8;
        float acc[8] = {0.f, 0.f, 0.f, 0.f, 0.f, 0.f, 0.f, 0.f};
        int j = a;
        for (; j + 4 <= bl; j += 4) {
            u32 w0 = cvs[j], w1 = cvs[j + 1], w2 = cvs[j + 2], w3 = cvs[j + 3];
            uint4 v0 = *(const uint4*)(xs + (size_t)(w0 >> 14) * 8);
            uint4 v1 = *(const uint4*)(xs + (size_t)(w1 >> 14) * 8);
            uint4 v2 = *(const uint4*)(xs + (size_t)(w2 >> 14) * 8);
            uint4 v3 = *(const uint4*)(xs + (size_t)(w3 >> 14) * 8);
            fma8(acc, v0, (float)(w0 & 16383u) * inv);
            fma8(acc, v1, (float)(w1 & 16383u) * inv);
            fma8(acc, v2, (float)(w2 & 16383u) * inv);
            fma8(acc, v3, (float)(w3 & 16383u) * inv);
        }
        for (; j < bl; ++j) {
            u32 w = cvs[j];
            uint4 v = *(const uint4*)(xs + (size_t)(w >> 14) * 8);
            fma8(acc, v, (float)(w & 16383u) * inv);
        }
        for (; j < b; ++j) {             // rare LDS-overflow tail
            u32 w = cvp[gbase + j];
            uint4 v = *(const uint4*)(xs + (size_t)(w >> 14) * 8);
            fma8(acc, v, (float)(w & 16383u) * inv);
        }
        if (active) {
            __half h8[8];
#pragma unroll
            for (int k = 0; k < 8; k++) h8[k] = __float2half(acc[k] * g);
            u4v pv = *(const u4v*)h8;
            __builtin_nontemporal_store(pv, (u4v*)(outt + ((size_t)s * N_ITEMS + r) * 8));
        }
    }
}

// ================= epilogue: acc = g0*emb + h1 + h2 + h3 (fp32, coalesced) =================

__global__ void k_epilogue(const __half* __restrict__ h1, const __half* __restrict__ h2,
                           const __half* __restrict__ h3, const float* __restrict__ emb,
                           const float* __restrict__ gamma, float* __restrict__ acc) {
    __shared__ float tile[TR][105];
    int base = blockIdx.x * TR;
    int tid = threadIdx.x;  // 256
    for (int p = tid; p < SLOTS * TR; p += 256) {
        int s = p / TR, rr = p - s * TR;
        int gr = base + rr;
        if (gr < N_ITEMS) {
            size_t off = ((size_t)s * N_ITEMS + gr) * 8;
            uint4 va = *(const uint4*)(h1 + off);
            uint4 vb = *(const uint4*)(h2 + off);
            uint4 vc = *(const uint4*)(h3 + off);
            const __half2* ap = (const __half2*)&va;
            const __half2* bp = (const __half2*)&vb;
            const __half2* cp = (const __half2*)&vc;
#pragma unroll
            for (int k = 0; k < 4; k++) {
                float2 pa = __half22float2(ap[k]);
                float2 pb = __half22float2(bp[k]);
                float2 pc = __half22float2(cp[k]);
                tile[rr][s * 8 + 2 * k]     = pa.x + pb.x + pc.x;
                tile[rr][s * 8 + 2 * k + 1] = pa.y + pb.y + pc.y;
            }
        }
    }
    __syncthreads();
    float g0 = gamma[0];
    for (int idx = tid; idx < TR * EMB; idx += 256) {
        int rr = idx / EMB, e = idx - rr * EMB;
        int gr = base + rr;
        if (gr < N_ITEMS)
            acc[(size_t)gr * EMB + e] = g0 * emb[(size_t)gr * EMB + e] + tile[rr][e];
    }
}

// ================= fallback atomic path (also used for tiny hist SpMM) =================

__global__ void k_init_acc(const float* __restrict__ emb,
                           const float* __restrict__ gamma,
                           float* __restrict__ acc, int n4) {
    int t = blockIdx.x * blockDim.x + threadIdx.x;
    if (t >= n4) return;
    float g = gamma[0];
    float4 v = ((const float4*)emb)[t];
    v.x *= g; v.y *= g; v.z *= g; v.w *= g;
    ((float4*)acc)[t] = v;
}

__global__ void k_acc_add(float* __restrict__ acc,
                          const float* __restrict__ item, int n4) {
    int t = blockIdx.x * blockDim.x + threadIdx.x;
    if (t >= n4) return;
    float4 a = ((float4*)acc)[t];
    float4 b = ((const float4*)item)[t];
    a.x += b.x; a.y += b.y; a.z += b.z; a.w += b.w;
    ((float4*)acc)[t] = a;
}

__global__ void k_spmm_atomic(const int* __restrict__ row,
                              const int* __restrict__ col,
                              const float* __restrict__ val,
                              const float* __restrict__ gamma, int gidx,
                              const float* __restrict__ x,
                              float* __restrict__ out, int nnz) {
    long long t = (long long)blockIdx.x * blockDim.x + threadIdx.x;
    long long total = (long long)nnz * EMB4;
    if (t >= total) return;
    int n = (int)(t / EMB4);
    int q = (int)(t % EMB4);
    int r = row[n];
    int c = col[n];
    float s = (gidx >= 0) ? gamma[gidx] : 1.0f;
    float v = val[n] * s;
    float4 xv = ((const float4*)x)[c * EMB4 + q];
    float* o = out + (long long)r * EMB + q * 4;
    atomicAdd(o + 0, v * xv.x);
    atomicAdd(o + 1, v * xv.y);
    atomicAdd(o + 2, v * xv.z);
    atomicAdd(o + 3, v * xv.w);
}

// ================= attention head =================
__global__ void k_attn(const float* __restrict__ hist_emb,   // [B*H, EMB]
                       const int* __restrict__ hist_len,
                       const int* __restrict__ user,
                       const float* __restrict__ user_emb,   // [N_USERS, EMB]
                       const float* __restrict__ W1,         // [2*EMB]
                       float* __restrict__ out_user) {       // [B, EMB]
    __shared__ float w[2 * EMB];
    __shared__ float he[HIST_MAX * EMB];
    __shared__ float alpha[HIST_MAX];
    __shared__ float ued, mx, sm;
    int b = blockIdx.x;
    int tid = threadIdx.x;

    for (int i = tid; i < 2 * EMB; i += blockDim.x) w[i] = W1[i];
    for (int i = tid; i < HIST_MAX * EMB; i += blockDim.x)
        he[i] = hist_emb[(long long)b * HIST_MAX * EMB + i];
    __syncthreads();

    if (tid == 0) {
        const float* ue = user_emb + (long long)user[b] * EMB;
        float s = 0.f;
        for (int e = 0; e < EMB; e++) s += ue[e] * w[e];
        ued = s;
    }
    __syncthreads();

    int len = hist_len[b];
    if (tid < HIST_MAX) {
        float d = 0.f;
        for (int e = 0; e < EMB; e++) d += he[tid * EMB + e] * w[EMB + e];
        alpha[tid] = ued + d + (tid >= len ? -99999.0f : 0.0f);
    }
    __syncthreads();

    if (tid == 0) {
        float m = -1e30f;
        for (int h = 0; h < HIST_MAX; h++) m = fmaxf(m, alpha[h]);
        mx = m;
    }
    __syncthreads();
    if (tid < HIST_MAX) alpha[tid] = expf(alpha[tid] - mx);
    __syncthreads();
    if (tid == 0) {
        float s = 0.f;
        for (int h = 0; h < HIST_MAX; h++) s += alpha[h];
        sm = s;
    }
    __syncthreads();

    float denom = (len == 0) ? 1.0f : (float)len;
    if (tid < EMB) {
        float s = 0.f;
        for (int h = 0; h < HIST_MAX; h++) s += alpha[h] * he[h * EMB + tid];
        out_user[(long long)b * EMB + tid] = s / (sm * denom);
    }
}

extern "C" void kernel_launch(void* const* d_in, const int* in_sizes, int n_in,
                              void* d_out, int out_size, void* d_ws, size_t ws_size,
                              hipStream_t stream) {
    const int*   adj_row  = (const int*)d_in[0];
    const int*   adj_col  = (const int*)d_in[1];
    const float* adj_val  = (const float*)d_in[2];
    const int*   hist_row = (const int*)d_in[3];
    const int*   hist_col = (const int*)d_in[4];
    const float* hist_val = (const float*)d_in[5];
    const int*   hist_len = (const int*)d_in[6];
    const int*   user     = (const int*)d_in[7];
    const float* embedding      = (const float*)d_in[8];
    const float* user_embedding = (const float*)d_in[9];
    const float* gamma    = (const float*)d_in[10];
    const float* W1       = (const float*)d_in[11];

    float* acc      = (float*)d_out;            // item_embeddings [200000,100]
    float* user_out = acc + ITEM_ELEMS;         // [100,100]

    int nnzA = in_sizes[0];
    int nnzH = in_sizes[3];

    // workspace layout
    // main path: 4 transposed fp16 tables (4 x 41.6MB).
    // fallback path overlays its two fp32 buffers on the same region.
    const size_t HBT = (size_t)SLOTS * N_ITEMS * 8 * sizeof(__half);  // 41,600,000
    char* ws = (char*)d_ws;
    __half* hb0 = (__half*)(ws + 0 * HBT);
    __half* hb1 = (__half*)(ws + 1 * HBT);
    __half* hb2 = (__half*)(ws + 2 * HBT);
    __half* hb3 = (__half*)(ws + 3 * HBT);
    float*  buf1 = (float*)(ws + 0);            // fallback only
    float*  buf2 = (float*)(ws + 80000000ULL);  // fallback only
    size_t off = 4 * HBT;                        // 166,400,000
    u32*   cvp  = (u32*)(ws + off);       off += (size_t)nnzA * 4;        // packed CSR
    int*   rowptr = (int*)(ws + off);     off += ((size_t)N_ITEMS + 4) * 4;
    int*   cnt  = (int*)(ws + off);       off += (size_t)N_ITEMS * 4;
    int*   blocksum = (int*)(ws + off);   off += 256 * 4;
    float* histe = (float*)(ws + off);    off += (size_t)BATCH * HIST_MAX * EMB * 4;
    size_t need_csr = off;

    const int n4 = ITEM_ELEMS / 4;
    long long totH = (long long)nnzH * EMB4;
    int blocksH = (int)((totH + 255) / 256);

    if (ws_size >= need_csr) {
        // ---------- CSR + banded fp16 gather path ----------
        hipMemsetAsync(cnt, 0, (size_t)N_ITEMS * 4, stream);
        hipMemsetAsync(histe, 0, (size_t)BATCH * HIST_MAX * EMB * 4, stream);

        int bN = (nnzA + 255) / 256;
        k_histogram<<<bN, 256, 0, stream>>>(adj_row, cnt, nnzA);
        k_scan_local<<<NSCAN_BLOCKS, SCAN_B, 0, stream>>>(cnt, rowptr, blocksum, N_ITEMS);
        k_scan_blocks<<<1, 256, 0, stream>>>(blocksum, NSCAN_BLOCKS);
        k_scan_add<<<(N_ITEMS + 255) / 256, 256, 0, stream>>>(rowptr, blocksum, N_ITEMS);
        k_fill<<<bN, 256, 0, stream>>>(adj_row, adj_col, adj_val, rowptr, cnt, cvp, nnzA);

        int trBlocks = (N_ITEMS + TR - 1) / TR;      // 3125
        int gBlocks = (N_ITEMS + GROWS - 1) / GROWS; // 1563 -> fully co-resident
        k_to_half_t<<<trBlocks, 256, 0, stream>>>(embedding, hb0);
        k_spmm_banded<<<gBlocks, GROWS, 0, stream>>>(rowptr, cvp, hb0, gamma, 1, hb1);
        k_spmm_banded<<<gBlocks, GROWS, 0, stream>>>(rowptr, cvp, hb1, gamma, 2, hb2);
        k_spmm_banded<<<gBlocks, GROWS, 0, stream>>>(rowptr, cvp, hb2, gamma, 3, hb3);
        k_epilogue<<<trBlocks, 256, 0, stream>>>(hb1, hb2, hb3, embedding, gamma, acc);
    } else {
        // ---------- fallback atomic path (fp32 throughout) ----------
        hipMemsetAsync(buf1, 0, 80000000ULL, stream);
        hipMemsetAsync(buf2, 0, 80000000ULL, stream);
        hipMemsetAsync(histe, 0, (size_t)BATCH * HIST_MAX * EMB * 4, stream);

        k_init_acc<<<(n4 + 255) / 256, 256, 0, stream>>>(embedding, gamma, acc, n4);
        long long totA = (long long)nnzA * EMB4;
        int blocksA = (int)((totA + 255) / 256);
        k_spmm_atomic<<<blocksA, 256, 0, stream>>>(adj_row, adj_col, adj_val, gamma, 1,
                                                   embedding, buf1, nnzA);
        k_acc_add<<<(n4 + 255) / 256, 256, 0, stream>>>(acc, buf1, n4);
        k_spmm_atomic<<<blocksA, 256, 0, stream>>>(adj_row, adj_col, adj_val, gamma, 2,
                                                   buf1, buf2, nnzA);
        k_acc_add<<<(n4 + 255) / 256, 256, 0, stream>>>(acc, buf2, n4);
        k_spmm_atomic<<<blocksA, 256, 0, stream>>>(adj_row, adj_col, adj_val, gamma, 3,
                                                   buf2, acc, nnzA);
    }

    // hist_emb = H @ item_embeddings (tiny, atomic scatter is fine)
    k_spmm_atomic<<<blocksH, 256, 0, stream>>>(hist_row, hist_col, hist_val, gamma, -1,
                                               acc, histe, nnzH);

    // attention head
    k_attn<<<BATCH, 128, 0, stream>>>(histe, hist_len, user, user_embedding, W1, user_out);
}

// Round 6
// 2383.207 us; speedup vs baseline: 1.5102x; 1.5102x over previous
//
#include <hip/hip_runtime.h>
#include <hip/hip_fp16.h>

#define EMB 100
#define EMB4 25            // EMB/4 float4s per row (fp32 layouts)
#define SLOTS 13           // ceil(EMB/8) slots of 8 halves per row
#define PADH 104           // padded halves per row (13*8)
#define N_ITEMS 200000
#define BATCH 100
#define HIST_MAX 50
#define ITEM_ELEMS 20000000  // N_ITEMS * EMB
#define SCAN_B 1024
#define NSCAN_BLOCKS ((N_ITEMS + SCAN_B - 1) / SCAN_B)   // 196 (< 256)
#define RPB 128            // rows per fill-bucket
#define NB_FILL ((N_ITEMS + RPB - 1) / RPB)              // 1563
#define VALQ 16383.0f      // 14-bit val quantization (validated in r4: absmax 0.125)

typedef unsigned int u32;
typedef unsigned long long u64;

// ================= CSR build =================

__global__ void k_histogram(const int* __restrict__ row, int* __restrict__ cnt, int nnz) {
    int i = blockIdx.x * blockDim.x + threadIdx.x;
    if (i < nnz) atomicAdd(&cnt[row[i]], 1);
}

// per-block inclusive scan; writes rowptr[i+1] (pre-offset) and block sum
__global__ void k_scan_local(const int* __restrict__ cnt, int* __restrict__ rowptr,
                             int* __restrict__ blocksum, int n) {
    __shared__ int sd[SCAN_B];
    int b = blockIdx.x, tid = threadIdx.x;
    int i = b * SCAN_B + tid;
    int v = (i < n) ? cnt[i] : 0;
    sd[tid] = v;
    __syncthreads();
    for (int off = 1; off < SCAN_B; off <<= 1) {
        int t = (tid >= off) ? sd[tid - off] : 0;
        __syncthreads();
        sd[tid] += t;
        __syncthreads();
    }
    if (i < n) rowptr[i + 1] = sd[tid];
    if (tid == SCAN_B - 1) blocksum[b] = sd[tid];
}

// single block: exclusive scan of <=256 block sums in place
__global__ void k_scan_blocks(int* __restrict__ blocksum, int nb) {
    __shared__ int sd[256];
    int tid = threadIdx.x;
    int v = (tid < nb) ? blocksum[tid] : 0;
    sd[tid] = v;
    __syncthreads();
    for (int off = 1; off < 256; off <<= 1) {
        int t = (tid >= off) ? sd[tid - off] : 0;
        __syncthreads();
        sd[tid] += t;
        __syncthreads();
    }
    if (tid < nb) blocksum[tid] = sd[tid] - v;  // exclusive
}

__global__ void k_scan_add(int* __restrict__ rowptr, const int* __restrict__ blocksum, int n) {
    int i = blockIdx.x * blockDim.x + threadIdx.x;
    if (i == 0) rowptr[0] = 0;
    if (i < n) rowptr[i + 1] += blocksum[i / SCAN_B];
}

// -------- two-phase fill (replaces random-scatter k_fill) --------
// Phase 1: append entry to its 128-row bucket's contiguous stage slice.
// Appends to a bucket are temporally clustered -> lines fill while L2-resident
// -> writeback ~= payload instead of 8x amplification.
__global__ void k_append(const int* __restrict__ row, const int* __restrict__ col,
                         const float* __restrict__ val, const int* __restrict__ rowptr,
                         int* __restrict__ btail, u64* __restrict__ stage, int nnz) {
    int i = blockIdx.x * blockDim.x + threadIdx.x;
    if (i >= nnz) return;
    int r = row[i];
    int b = r >> 7;                         // bucket of 128 rows
    int base = rowptr[b << 7];              // bucket's CSR base
    int pos = base + atomicAdd(&btail[b], 1);
    u32 q = (u32)__float2uint_rn(val[i] * VALQ);
    u32 cv = ((u32)col[i] << 14) | q;
    stage[pos] = ((u64)(u32)(r & (RPB - 1)) << 32) | cv;
}

// Phase 2: one block per bucket; coalesced stage read; final pos via LDS cursor;
// scattered writes confined to the bucket's ~16KB CSR window (write-combines).
__global__ __launch_bounds__(256)
void k_place(const u64* __restrict__ stage, const int* __restrict__ rowptr,
             u32* __restrict__ cvp) {
    __shared__ int cur[RPB];
    int b = blockIdx.x;
    int r0 = b << 7;
    int tid = threadIdx.x;
    if (tid < RPB) {
        int gr = r0 + tid;
        cur[tid] = (gr < N_ITEMS) ? rowptr[gr] : 0;
    }
    __syncthreads();
    int rend = (r0 + RPB < N_ITEMS) ? (r0 + RPB) : N_ITEMS;
    int base = rowptr[r0];
    int end  = rowptr[rend];
    for (int j = base + tid; j < end; j += 256) {
        u64 e = stage[j];
        int rl = (int)(e >> 32);
        u32 cv = (u32)e;
        int pos = atomicAdd(&cur[rl], 1);
        cvp[pos] = cv;
    }
}

// ================= fp32 -> padded fp16 row conversion =================
// dst rows: 104 halves (elements 100..103 zero-padded)
__global__ void k_to_half(const float* __restrict__ src, __half* __restrict__ dst) {
    int t = blockIdx.x * blockDim.x + threadIdx.x;
    if (t >= N_ITEMS * SLOTS) return;
    int r = t / SLOTS;
    int sl = t - r * SLOTS;
    int e0 = sl * 8;
    const float* s = src + r * EMB;
    __half h[8];
#pragma unroll
    for (int k = 0; k < 8; k++) {
        int e = e0 + k;
        h[k] = __float2half((e < EMB) ? s[e] : 0.f);
    }
    *(uint4*)(dst + r * PADH + e0) = *(const uint4*)h;
}

// ================= gather SpMM (fp16 x-table, packed 4B cvp) =================
// thread t -> (row r = t/13, 8-half slot sl = t%13). 13 lanes per row read a
// contiguous 208B row segment -> full cache-line utilization on the gather.
// acc!=null => final mode: acc = g0*emb + h1 + h2 + g[gidx]*sum  (fp32 out)
// else      => outh = fp16(g[gidx]*sum)

__device__ __forceinline__ void fma8(float s[8], const uint4& hv, float f) {
    const __half2* hp = reinterpret_cast<const __half2*>(&hv);
#pragma unroll
    for (int k = 0; k < 4; k++) {
        float2 p = __half22float2(hp[k]);
        s[2 * k]     += f * p.x;
        s[2 * k + 1] += f * p.y;
    }
}

__global__ void k_spmm_gather_h(const int* __restrict__ rowptr, const u32* __restrict__ cvp,
                                const __half* __restrict__ x,
                                const float* __restrict__ gamma, int gidx,
                                __half* __restrict__ outh,
                                const float* __restrict__ emb,
                                const __half* __restrict__ h1, const __half* __restrict__ h2,
                                float* __restrict__ acc) {
    int t = blockIdx.x * blockDim.x + threadIdx.x;
    if (t >= N_ITEMS * SLOTS) return;
    int r = t / SLOTS;
    int sl = t - r * SLOTS;
    int e0 = sl * 8;
    int j0 = rowptr[r], j1 = rowptr[r + 1];
    const float inv = 1.0f / VALQ;
    float s[8] = {0.f, 0.f, 0.f, 0.f, 0.f, 0.f, 0.f, 0.f};
    int j = j0;
    for (; j + 4 <= j1; j += 4) {
        u32 w0 = cvp[j + 0];
        u32 w1 = cvp[j + 1];
        u32 w2 = cvp[j + 2];
        u32 w3 = cvp[j + 3];
        uint4 v0 = *(const uint4*)(x + (w0 >> 14) * PADH + e0);
        uint4 v1 = *(const uint4*)(x + (w1 >> 14) * PADH + e0);
        uint4 v2 = *(const uint4*)(x + (w2 >> 14) * PADH + e0);
        uint4 v3 = *(const uint4*)(x + (w3 >> 14) * PADH + e0);
        fma8(s, v0, (float)(w0 & 16383u) * inv);
        fma8(s, v1, (float)(w1 & 16383u) * inv);
        fma8(s, v2, (float)(w2 & 16383u) * inv);
        fma8(s, v3, (float)(w3 & 16383u) * inv);
    }
    for (; j < j1; ++j) {
        u32 w = cvp[j];
        uint4 v = *(const uint4*)(x + (w >> 14) * PADH + e0);
        fma8(s, v, (float)(w & 16383u) * inv);
    }
    float g = gamma[gidx];
#pragma unroll
    for (int k = 0; k < 8; k++) s[k] *= g;

    if (acc) {
        float g0 = gamma[0];
        uint4 a = *(const uint4*)(h1 + r * PADH + e0);
        uint4 b = *(const uint4*)(h2 + r * PADH + e0);
        const __half2* ap = reinterpret_cast<const __half2*>(&a);
        const __half2* bp = reinterpret_cast<const __half2*>(&b);
        float o[8];
#pragma unroll
        for (int k = 0; k < 4; k++) {
            float2 pa = __half22float2(ap[k]);
            float2 pb = __half22float2(bp[k]);
            o[2 * k]     = s[2 * k]     + pa.x + pb.x;
            o[2 * k + 1] = s[2 * k + 1] + pa.y + pb.y;
        }
        const float* ep = emb + r * EMB + e0;
        float* op = acc + r * EMB + e0;
        float4 e1v = *(const float4*)(ep);
        float4 w1v = make_float4(o[0] + g0 * e1v.x, o[1] + g0 * e1v.y,
                                 o[2] + g0 * e1v.z, o[3] + g0 * e1v.w);
        *(float4*)(op) = w1v;
        if (e0 + 8 <= EMB) {   // last slot (e0=96) writes only 4 valid floats
            float4 e2v = *(const float4*)(ep + 4);
            float4 w2v = make_float4(o[4] + g0 * e2v.x, o[5] + g0 * e2v.y,
                                     o[6] + g0 * e2v.z, o[7] + g0 * e2v.w);
            *(float4*)(op + 4) = w2v;
        }
    } else {
        __half hh[8];
#pragma unroll
        for (int k = 0; k < 8; k++) hh[k] = __float2half(s[k]);
        *(uint4*)(outh + r * PADH + e0) = *(const uint4*)hh;
    }
}

// ================= fallback atomic path (also used for tiny hist SpMM) =================

__global__ void k_init_acc(const float* __restrict__ emb,
                           const float* __restrict__ gamma,
                           float* __restrict__ acc, int n4) {
    int t = blockIdx.x * blockDim.x + threadIdx.x;
    if (t >= n4) return;
    float g = gamma[0];
    float4 v = ((const float4*)emb)[t];
    v.x *= g; v.y *= g; v.z *= g; v.w *= g;
    ((float4*)acc)[t] = v;
}

__global__ void k_acc_add(float* __restrict__ acc,
                          const float* __restrict__ item, int n4) {
    int t = blockIdx.x * blockDim.x + threadIdx.x;
    if (t >= n4) return;
    float4 a = ((float4*)acc)[t];
    float4 b = ((const float4*)item)[t];
    a.x += b.x; a.y += b.y; a.z += b.z; a.w += b.w;
    ((float4*)acc)[t] = a;
}

__global__ void k_spmm_atomic(const int* __restrict__ row,
                              const int* __restrict__ col,
                              const float* __restrict__ val,
                              const float* __restrict__ gamma, int gidx,
                              const float* __restrict__ x,
                              float* __restrict__ out, int nnz) {
    long long t = (long long)blockIdx.x * blockDim.x + threadIdx.x;
    long long total = (long long)nnz * EMB4;
    if (t >= total) return;
    int n = (int)(t / EMB4);
    int q = (int)(t % EMB4);
    int r = row[n];
    int c = col[n];
    float s = (gidx >= 0) ? gamma[gidx] : 1.0f;
    float v = val[n] * s;
    float4 xv = ((const float4*)x)[c * EMB4 + q];
    float* o = out + (long long)r * EMB + q * 4;
    atomicAdd(o + 0, v * xv.x);
    atomicAdd(o + 1, v * xv.y);
    atomicAdd(o + 2, v * xv.z);
    atomicAdd(o + 3, v * xv.w);
}

// ================= attention head =================
__global__ void k_attn(const float* __restrict__ hist_emb,   // [B*H, EMB]
                       const int* __restrict__ hist_len,
                       const int* __restrict__ user,
                       const float* __restrict__ user_emb,   // [N_USERS, EMB]
                       const float* __restrict__ W1,         // [2*EMB]
                       float* __restrict__ out_user) {       // [B, EMB]
    __shared__ float w[2 * EMB];
    __shared__ float he[HIST_MAX * EMB];
    __shared__ float alpha[HIST_MAX];
    __shared__ float ued, mx, sm;
    int b = blockIdx.x;
    int tid = threadIdx.x;

    for (int i = tid; i < 2 * EMB; i += blockDim.x) w[i] = W1[i];
    for (int i = tid; i < HIST_MAX * EMB; i += blockDim.x)
        he[i] = hist_emb[(long long)b * HIST_MAX * EMB + i];
    __syncthreads();

    if (tid == 0) {
        const float* ue = user_emb + (long long)user[b] * EMB;
        float s = 0.f;
        for (int e = 0; e < EMB; e++) s += ue[e] * w[e];
        ued = s;
    }
    __syncthreads();

    int len = hist_len[b];
    if (tid < HIST_MAX) {
        float d = 0.f;
        for (int e = 0; e < EMB; e++) d += he[tid * EMB + e] * w[EMB + e];
        alpha[tid] = ued + d + (tid >= len ? -99999.0f : 0.0f);
    }
    __syncthreads();

    if (tid == 0) {
        float m = -1e30f;
        for (int h = 0; h < HIST_MAX; h++) m = fmaxf(m, alpha[h]);
        mx = m;
    }
    __syncthreads();
    if (tid < HIST_MAX) alpha[tid] = expf(alpha[tid] - mx);
    __syncthreads();
    if (tid == 0) {
        float s = 0.f;
        for (int h = 0; h < HIST_MAX; h++) s += alpha[h];
        sm = s;
    }
    __syncthreads();

    float denom = (len == 0) ? 1.0f : (float)len;
    if (tid < EMB) {
        float s = 0.f;
        for (int h = 0; h < HIST_MAX; h++) s += alpha[h] * he[h * EMB + tid];
        out_user[(long long)b * EMB + tid] = s / (sm * denom);
    }
}

extern "C" void kernel_launch(void* const* d_in, const int* in_sizes, int n_in,
                              void* d_out, int out_size, void* d_ws, size_t ws_size,
                              hipStream_t stream) {
    const int*   adj_row  = (const int*)d_in[0];
    const int*   adj_col  = (const int*)d_in[1];
    const float* adj_val  = (const float*)d_in[2];
    const int*   hist_row = (const int*)d_in[3];
    const int*   hist_col = (const int*)d_in[4];
    const float* hist_val = (const float*)d_in[5];
    const int*   hist_len = (const int*)d_in[6];
    const int*   user     = (const int*)d_in[7];
    const float* embedding      = (const float*)d_in[8];
    const float* user_embedding = (const float*)d_in[9];
    const float* gamma    = (const float*)d_in[10];
    const float* W1       = (const float*)d_in[11];

    float* acc      = (float*)d_out;            // item_embeddings [200000,100]
    float* user_out = acc + ITEM_ELEMS;         // [100,100]

    int nnzA = in_sizes[0];
    int nnzH = in_sizes[3];

    // workspace layout
    // main path: 3 fp16 tables hb0..hb2 (41.6MB each). The 8B stage buffer for
    // the two-phase fill overlays hb1+hb2 (dead until the gathers run).
    // fallback path overlays its two fp32 buffers on the same region.
    const size_t HBT = (size_t)N_ITEMS * PADH * sizeof(__half);  // 41,600,000
    char* ws = (char*)d_ws;
    __half* hb0 = (__half*)(ws + 0 * HBT);
    __half* hb1 = (__half*)(ws + 1 * HBT);
    __half* hb2 = (__half*)(ws + 2 * HBT);
    u64*    stage = (u64*)(ws + 1 * HBT);       // overlays hb1/hb2 (needs nnz*8 <= 2*HBT)
    float*  buf1 = (float*)(ws + 0);            // fallback only
    float*  buf2 = (float*)(ws + 80000000ULL);  // fallback only
    size_t off = 3 * HBT;                        // 124,800,000
    u32*   cvp  = (u32*)(ws + off);       off += (size_t)nnzA * 4;        // packed CSR
    int*   rowptr = (int*)(ws + off);     off += ((size_t)N_ITEMS + 4) * 4;
    int*   cnt  = (int*)(ws + off);       off += (size_t)N_ITEMS * 4;     // cnt..btail one memset
    int*   btail = (int*)(ws + off);      off += (size_t)(NB_FILL + 64) * 4;
    int*   blocksum = (int*)(ws + off);   off += 256 * 4;
    float* histe = (float*)(ws + off);    off += (size_t)BATCH * HIST_MAX * EMB * 4;
    size_t need_csr = off;
    if ((size_t)nnzA * 8 > 2 * HBT) need_csr = (size_t)1 << 62;  // stage overlay wouldn't fit

    const int n4 = ITEM_ELEMS / 4;
    long long totH = (long long)nnzH * EMB4;
    int blocksH = (int)((totH + 255) / 256);

    if (ws_size >= need_csr) {
        // ---------- CSR (two-phase fill) + fp16 gather path ----------
        hipMemsetAsync(cnt, 0, ((size_t)N_ITEMS + NB_FILL + 64) * 4, stream);
        hipMemsetAsync(histe, 0, (size_t)BATCH * HIST_MAX * EMB * 4, stream);

        int bN = (nnzA + 255) / 256;
        k_histogram<<<bN, 256, 0, stream>>>(adj_row, cnt, nnzA);
        k_scan_local<<<NSCAN_BLOCKS, SCAN_B, 0, stream>>>(cnt, rowptr, blocksum, N_ITEMS);
        k_scan_blocks<<<1, 256, 0, stream>>>(blocksum, NSCAN_BLOCKS);
        k_scan_add<<<(N_ITEMS + 255) / 256, 256, 0, stream>>>(rowptr, blocksum, N_ITEMS);
        k_append<<<bN, 256, 0, stream>>>(adj_row, adj_col, adj_val, rowptr, btail, stage, nnzA);
        k_place<<<NB_FILL, 256, 0, stream>>>(stage, rowptr, cvp);

        int gThreads = N_ITEMS * SLOTS;          // 2.6M
        int gBlocks = (gThreads + 255) / 256;
        // embedding -> fp16 padded table
        k_to_half<<<gBlocks, 256, 0, stream>>>(embedding, hb0);
        // layer 1: hb1 = fp16(g1 * A @ hb0)   (stage is dead from here)
        k_spmm_gather_h<<<gBlocks, 256, 0, stream>>>(rowptr, cvp, hb0, gamma, 1,
                                                     hb1, nullptr, nullptr, nullptr, nullptr);
        // layer 2: hb2 = fp16(g2 * A @ hb1)
        k_spmm_gather_h<<<gBlocks, 256, 0, stream>>>(rowptr, cvp, hb1, gamma, 2,
                                                     hb2, nullptr, nullptr, nullptr, nullptr);
        // layer 3 + fused epilogue: acc = g0*emb + hb1 + hb2 + g3 * A @ hb2   (fp32 out)
        k_spmm_gather_h<<<gBlocks, 256, 0, stream>>>(rowptr, cvp, hb2, gamma, 3,
                                                     nullptr, embedding, hb1, hb2, acc);
    } else {
        // ---------- fallback atomic path (fp32 throughout) ----------
        hipMemsetAsync(buf1, 0, 80000000ULL, stream);
        hipMemsetAsync(buf2, 0, 80000000ULL, stream);
        hipMemsetAsync(histe, 0, (size_t)BATCH * HIST_MAX * EMB * 4, stream);

        k_init_acc<<<(n4 + 255) / 256, 256, 0, stream>>>(embedding, gamma, acc, n4);
        long long totA = (long long)nnzA * EMB4;
        int blocksA = (int)((totA + 255) / 256);
        k_spmm_atomic<<<blocksA, 256, 0, stream>>>(adj_row, adj_col, adj_val, gamma, 1,
                                                   embedding, buf1, nnzA);
        k_acc_add<<<(n4 + 255) / 256, 256, 0, stream>>>(acc, buf1, n4);
        k_spmm_atomic<<<blocksA, 256, 0, stream>>>(adj_row, adj_col, adj_val, gamma, 2,
                                                   buf1, buf2, nnzA);
        k_acc_add<<<(n4 + 255) / 256, 256, 0, stream>>>(acc, buf2, n4);
        k_spmm_atomic<<<blocksA, 256, 0, stream>>>(adj_row, adj_col, adj_val, gamma, 3,
                                                   buf2, acc, nnzA);
    }

    // hist_emb = H @ item_embeddings (tiny, atomic scatter is fine)
    k_spmm_atomic<<<blocksH, 256, 0, stream>>>(hist_row, hist_col, hist_val, gamma, -1,
                                               acc, histe, nnzH);

    // attention head
    k_attn<<<BATCH, 128, 0, stream>>>(histe, hist_len, user, user_embedding, W1, user_out);
}

// Round 7
// 1733.776 us; speedup vs baseline: 2.0759x; 1.3746x over previous
//
#include <hip/hip_runtime.h>
#include <hip/hip_fp16.h>

#define EMB 100
#define EMB4 25            // EMB/4 float4s per row (fp32 layouts)
#define SLOTS 13           // ceil(EMB/8) slots of 8 halves per row
#define PADH 104           // padded halves per row (13*8)
#define N_ITEMS 200000
#define BATCH 100
#define HIST_MAX 50
#define ITEM_ELEMS 20000000  // N_ITEMS * EMB
#define SCAN_B 1024
#define NSCAN_BLOCKS ((N_ITEMS + SCAN_B - 1) / SCAN_B)   // 196 (< 256)
#define VALQ 16383.0f      // 14-bit val quantization (validated: absmax 0.125)

typedef unsigned int u32;

// ================= CSR build =================

__global__ void k_histogram(const int* __restrict__ row, int* __restrict__ cnt, int nnz) {
    int i = blockIdx.x * blockDim.x + threadIdx.x;
    if (i < nnz) atomicAdd(&cnt[row[i]], 1);
}

// per-block inclusive scan; writes rowptr[i+1] (pre-offset) and block sum
__global__ void k_scan_local(const int* __restrict__ cnt, int* __restrict__ rowptr,
                             int* __restrict__ blocksum, int n) {
    __shared__ int sd[SCAN_B];
    int b = blockIdx.x, tid = threadIdx.x;
    int i = b * SCAN_B + tid;
    int v = (i < n) ? cnt[i] : 0;
    sd[tid] = v;
    __syncthreads();
    for (int off = 1; off < SCAN_B; off <<= 1) {
        int t = (tid >= off) ? sd[tid - off] : 0;
        __syncthreads();
        sd[tid] += t;
        __syncthreads();
    }
    if (i < n) rowptr[i + 1] = sd[tid];
    if (tid == SCAN_B - 1) blocksum[b] = sd[tid];
}

// single block: exclusive scan of <=256 block sums in place
__global__ void k_scan_blocks(int* __restrict__ blocksum, int nb) {
    __shared__ int sd[256];
    int tid = threadIdx.x;
    int v = (tid < nb) ? blocksum[tid] : 0;
    sd[tid] = v;
    __syncthreads();
    for (int off = 1; off < 256; off <<= 1) {
        int t = (tid >= off) ? sd[tid - off] : 0;
        __syncthreads();
        sd[tid] += t;
        __syncthreads();
    }
    if (tid < nb) blocksum[tid] = sd[tid] - v;  // exclusive
}

__global__ void k_scan_add(int* __restrict__ rowptr, const int* __restrict__ blocksum, int n) {
    int i = blockIdx.x * blockDim.x + threadIdx.x;
    if (i == 0) rowptr[0] = 0;
    if (i < n) rowptr[i + 1] += blocksum[i / SCAN_B];
}

// fill CSR using atomicSub on cnt (row length) -> atomics spread over 200K
// addresses (32/address — proven fine in r3; 1563 addresses was 230ns/op).
// 4B packed entry halves the scatter window vs r3's 8B -> ~2 stores/line/XCD.
__global__ void k_fill(const int* __restrict__ row, const int* __restrict__ col,
                       const float* __restrict__ val, const int* __restrict__ rowptr,
                       int* __restrict__ cnt, u32* __restrict__ cvp, int nnz) {
    int i = blockIdx.x * blockDim.x + threadIdx.x;
    if (i >= nnz) return;
    int r = row[i];
    int old = atomicSub(&cnt[r], 1);        // old in [1..len]
    int pos = rowptr[r] + old - 1;
    u32 q = (u32)__float2uint_rn(val[i] * VALQ);
    cvp[pos] = ((u32)col[i] << 14) | q;
}

// ================= fp32 -> padded fp16 row conversion =================
// dst rows: 104 halves (elements 100..103 zero-padded)
__global__ void k_to_half(const float* __restrict__ src, __half* __restrict__ dst) {
    int t = blockIdx.x * blockDim.x + threadIdx.x;
    if (t >= N_ITEMS * SLOTS) return;
    int r = t / SLOTS;
    int sl = t - r * SLOTS;
    int e0 = sl * 8;
    const float* s = src + r * EMB;
    __half h[8];
#pragma unroll
    for (int k = 0; k < 8; k++) {
        int e = e0 + k;
        h[k] = __float2half((e < EMB) ? s[e] : 0.f);
    }
    *(uint4*)(dst + r * PADH + e0) = *(const uint4*)h;
}

// ================= gather SpMM (fp16 x-table, packed 4B cvp) =================
// thread t -> (row r = t/13, 8-half slot sl = t%13). 13 lanes per row read a
// contiguous 208B row segment -> full cache-line utilization on the gather.
// acc!=null => final mode: acc = g0*emb + h1 + h2 + g[gidx]*sum  (fp32 out)
// else      => outh = fp16(g[gidx]*sum)

__device__ __forceinline__ void fma8(float s[8], const uint4& hv, float f) {
    const __half2* hp = reinterpret_cast<const __half2*>(&hv);
#pragma unroll
    for (int k = 0; k < 4; k++) {
        float2 p = __half22float2(hp[k]);
        s[2 * k]     += f * p.x;
        s[2 * k + 1] += f * p.y;
    }
}

__global__ void k_spmm_gather_h(const int* __restrict__ rowptr, const u32* __restrict__ cvp,
                                const __half* __restrict__ x,
                                const float* __restrict__ gamma, int gidx,
                                __half* __restrict__ outh,
                                const float* __restrict__ emb,
                                const __half* __restrict__ h1, const __half* __restrict__ h2,
                                float* __restrict__ acc) {
    int t = blockIdx.x * blockDim.x + threadIdx.x;
    if (t >= N_ITEMS * SLOTS) return;
    int r = t / SLOTS;
    int sl = t - r * SLOTS;
    int e0 = sl * 8;
    int j0 = rowptr[r], j1 = rowptr[r + 1];
    const float inv = 1.0f / VALQ;
    float s[8] = {0.f, 0.f, 0.f, 0.f, 0.f, 0.f, 0.f, 0.f};
    int j = j0;
    for (; j + 4 <= j1; j += 4) {
        u32 w0 = cvp[j + 0];
        u32 w1 = cvp[j + 1];
        u32 w2 = cvp[j + 2];
        u32 w3 = cvp[j + 3];
        uint4 v0 = *(const uint4*)(x + (w0 >> 14) * PADH + e0);
        uint4 v1 = *(const uint4*)(x + (w1 >> 14) * PADH + e0);
        uint4 v2 = *(const uint4*)(x + (w2 >> 14) * PADH + e0);
        uint4 v3 = *(const uint4*)(x + (w3 >> 14) * PADH + e0);
        fma8(s, v0, (float)(w0 & 16383u) * inv);
        fma8(s, v1, (float)(w1 & 16383u) * inv);
        fma8(s, v2, (float)(w2 & 16383u) * inv);
        fma8(s, v3, (float)(w3 & 16383u) * inv);
    }
    for (; j < j1; ++j) {
        u32 w = cvp[j];
        uint4 v = *(const uint4*)(x + (w >> 14) * PADH + e0);
        fma8(s, v, (float)(w & 16383u) * inv);
    }
    float g = gamma[gidx];
#pragma unroll
    for (int k = 0; k < 8; k++) s[k] *= g;

    if (acc) {
        float g0 = gamma[0];
        uint4 a = *(const uint4*)(h1 + r * PADH + e0);
        uint4 b = *(const uint4*)(h2 + r * PADH + e0);
        const __half2* ap = reinterpret_cast<const __half2*>(&a);
        const __half2* bp = reinterpret_cast<const __half2*>(&b);
        float o[8];
#pragma unroll
        for (int k = 0; k < 4; k++) {
            float2 pa = __half22float2(ap[k]);
            float2 pb = __half22float2(bp[k]);
            o[2 * k]     = s[2 * k]     + pa.x + pb.x;
            o[2 * k + 1] = s[2 * k + 1] + pa.y + pb.y;
        }
        const float* ep = emb + r * EMB + e0;
        float* op = acc + r * EMB + e0;
        float4 e1v = *(const float4*)(ep);
        float4 w1v = make_float4(o[0] + g0 * e1v.x, o[1] + g0 * e1v.y,
                                 o[2] + g0 * e1v.z, o[3] + g0 * e1v.w);
        *(float4*)(op) = w1v;
        if (e0 + 8 <= EMB) {   // last slot (e0=96) writes only 4 valid floats
            float4 e2v = *(const float4*)(ep + 4);
            float4 w2v = make_float4(o[4] + g0 * e2v.x, o[5] + g0 * e2v.y,
                                     o[6] + g0 * e2v.z, o[7] + g0 * e2v.w);
            *(float4*)(op + 4) = w2v;
        }
    } else {
        __half hh[8];
#pragma unroll
        for (int k = 0; k < 8; k++) hh[k] = __float2half(s[k]);
        *(uint4*)(outh + r * PADH + e0) = *(const uint4*)hh;
    }
}

// ================= fallback atomic path (also used for tiny hist SpMM) =================

__global__ void k_init_acc(const float* __restrict__ emb,
                           const float* __restrict__ gamma,
                           float* __restrict__ acc, int n4) {
    int t = blockIdx.x * blockDim.x + threadIdx.x;
    if (t >= n4) return;
    float g = gamma[0];
    float4 v = ((const float4*)emb)[t];
    v.x *= g; v.y *= g; v.z *= g; v.w *= g;
    ((float4*)acc)[t] = v;
}

__global__ void k_acc_add(float* __restrict__ acc,
                          const float* __restrict__ item, int n4) {
    int t = blockIdx.x * blockDim.x + threadIdx.x;
    if (t >= n4) return;
    float4 a = ((float4*)acc)[t];
    float4 b = ((const float4*)item)[t];
    a.x += b.x; a.y += b.y; a.z += b.z; a.w += b.w;
    ((float4*)acc)[t] = a;
}

__global__ void k_spmm_atomic(const int* __restrict__ row,
                              const int* __restrict__ col,
                              const float* __restrict__ val,
                              const float* __restrict__ gamma, int gidx,
                              const float* __restrict__ x,
                              float* __restrict__ out, int nnz) {
    long long t = (long long)blockIdx.x * blockDim.x + threadIdx.x;
    long long total = (long long)nnz * EMB4;
    if (t >= total) return;
    int n = (int)(t / EMB4);
    int q = (int)(t % EMB4);
    int r = row[n];
    int c = col[n];
    float s = (gidx >= 0) ? gamma[gidx] : 1.0f;
    float v = val[n] * s;
    float4 xv = ((const float4*)x)[c * EMB4 + q];
    float* o = out + (long long)r * EMB + q * 4;
    atomicAdd(o + 0, v * xv.x);
    atomicAdd(o + 1, v * xv.y);
    atomicAdd(o + 2, v * xv.z);
    atomicAdd(o + 3, v * xv.w);
}

// ================= attention head =================
__global__ void k_attn(const float* __restrict__ hist_emb,   // [B*H, EMB]
                       const int* __restrict__ hist_len,
                       const int* __restrict__ user,
                       const float* __restrict__ user_emb,   // [N_USERS, EMB]
                       const float* __restrict__ W1,         // [2*EMB]
                       float* __restrict__ out_user) {       // [B, EMB]
    __shared__ float w[2 * EMB];
    __shared__ float he[HIST_MAX * EMB];
    __shared__ float alpha[HIST_MAX];
    __shared__ float ued, mx, sm;
    int b = blockIdx.x;
    int tid = threadIdx.x;

    for (int i = tid; i < 2 * EMB; i += blockDim.x) w[i] = W1[i];
    for (int i = tid; i < HIST_MAX * EMB; i += blockDim.x)
        he[i] = hist_emb[(long long)b * HIST_MAX * EMB + i];
    __syncthreads();

    if (tid == 0) {
        const float* ue = user_emb + (long long)user[b] * EMB;
        float s = 0.f;
        for (int e = 0; e < EMB; e++) s += ue[e] * w[e];
        ued = s;
    }
    __syncthreads();

    int len = hist_len[b];
    if (tid < HIST_MAX) {
        float d = 0.f;
        for (int e = 0; e < EMB; e++) d += he[tid * EMB + e] * w[EMB + e];
        alpha[tid] = ued + d + (tid >= len ? -99999.0f : 0.0f);
    }
    __syncthreads();

    if (tid == 0) {
        float m = -1e30f;
        for (int h = 0; h < HIST_MAX; h++) m = fmaxf(m, alpha[h]);
        mx = m;
    }
    __syncthreads();
    if (tid < HIST_MAX) alpha[tid] = expf(alpha[tid] - mx);
    __syncthreads();
    if (tid == 0) {
        float s = 0.f;
        for (int h = 0; h < HIST_MAX; h++) s += alpha[h];
        sm = s;
    }
    __syncthreads();

    float denom = (len == 0) ? 1.0f : (float)len;
    if (tid < EMB) {
        float s = 0.f;
        for (int h = 0; h < HIST_MAX; h++) s += alpha[h] * he[h * EMB + tid];
        out_user[(long long)b * EMB + tid] = s / (sm * denom);
    }
}

extern "C" void kernel_launch(void* const* d_in, const int* in_sizes, int n_in,
                              void* d_out, int out_size, void* d_ws, size_t ws_size,
                              hipStream_t stream) {
    const int*   adj_row  = (const int*)d_in[0];
    const int*   adj_col  = (const int*)d_in[1];
    const float* adj_val  = (const float*)d_in[2];
    const int*   hist_row = (const int*)d_in[3];
    const int*   hist_col = (const int*)d_in[4];
    const float* hist_val = (const float*)d_in[5];
    const int*   hist_len = (const int*)d_in[6];
    const int*   user     = (const int*)d_in[7];
    const float* embedding      = (const float*)d_in[8];
    const float* user_embedding = (const float*)d_in[9];
    const float* gamma    = (const float*)d_in[10];
    const float* W1       = (const float*)d_in[11];

    float* acc      = (float*)d_out;            // item_embeddings [200000,100]
    float* user_out = acc + ITEM_ELEMS;         // [100,100]

    int nnzA = in_sizes[0];
    int nnzH = in_sizes[3];

    // workspace layout
    // main path: 3 fp16 tables hb0..hb2 (41.6MB each) + 4B packed cvp.
    // fallback path overlays its two fp32 buffers on the same region.
    const size_t HBT = (size_t)N_ITEMS * PADH * sizeof(__half);  // 41,600,000
    char* ws = (char*)d_ws;
    __half* hb0 = (__half*)(ws + 0 * HBT);
    __half* hb1 = (__half*)(ws + 1 * HBT);
    __half* hb2 = (__half*)(ws + 2 * HBT);
    float*  buf1 = (float*)(ws + 0);            // fallback only
    float*  buf2 = (float*)(ws + 80000000ULL);  // fallback only
    size_t off = 3 * HBT;                        // 124,800,000
    u32*   cvp  = (u32*)(ws + off);       off += (size_t)nnzA * 4;        // packed CSR
    int*   rowptr = (int*)(ws + off);     off += ((size_t)N_ITEMS + 4) * 4;
    int*   cnt  = (int*)(ws + off);       off += (size_t)N_ITEMS * 4;
    int*   blocksum = (int*)(ws + off);   off += 256 * 4;
    float* histe = (float*)(ws + off);    off += (size_t)BATCH * HIST_MAX * EMB * 4;
    size_t need_csr = off;

    const int n4 = ITEM_ELEMS / 4;
    long long totH = (long long)nnzH * EMB4;
    int blocksH = (int)((totH + 255) / 256);

    if (ws_size >= need_csr) {
        // ---------- CSR + fp16 gather path ----------
        hipMemsetAsync(cnt, 0, (size_t)N_ITEMS * 4, stream);
        hipMemsetAsync(histe, 0, (size_t)BATCH * HIST_MAX * EMB * 4, stream);

        int bN = (nnzA + 255) / 256;
        k_histogram<<<bN, 256, 0, stream>>>(adj_row, cnt, nnzA);
        k_scan_local<<<NSCAN_BLOCKS, SCAN_B, 0, stream>>>(cnt, rowptr, blocksum, N_ITEMS);
        k_scan_blocks<<<1, 256, 0, stream>>>(blocksum, NSCAN_BLOCKS);
        k_scan_add<<<(N_ITEMS + 255) / 256, 256, 0, stream>>>(rowptr, blocksum, N_ITEMS);
        k_fill<<<bN, 256, 0, stream>>>(adj_row, adj_col, adj_val, rowptr, cnt, cvp, nnzA);

        int gThreads = N_ITEMS * SLOTS;          // 2.6M
        int gBlocks = (gThreads + 255) / 256;
        // embedding -> fp16 padded table
        k_to_half<<<gBlocks, 256, 0, stream>>>(embedding, hb0);
        // layer 1: hb1 = fp16(g1 * A @ hb0)
        k_spmm_gather_h<<<gBlocks, 256, 0, stream>>>(rowptr, cvp, hb0, gamma, 1,
                                                     hb1, nullptr, nullptr, nullptr, nullptr);
        // layer 2: hb2 = fp16(g2 * A @ hb1)
        k_spmm_gather_h<<<gBlocks, 256, 0, stream>>>(rowptr, cvp, hb1, gamma, 2,
                                                     hb2, nullptr, nullptr, nullptr, nullptr);
        // layer 3 + fused epilogue: acc = g0*emb + hb1 + hb2 + g3 * A @ hb2   (fp32 out)
        k_spmm_gather_h<<<gBlocks, 256, 0, stream>>>(rowptr, cvp, hb2, gamma, 3,
                                                     nullptr, embedding, hb1, hb2, acc);
    } else {
        // ---------- fallback atomic path (fp32 throughout) ----------
        hipMemsetAsync(buf1, 0, 80000000ULL, stream);
        hipMemsetAsync(buf2, 0, 80000000ULL, stream);
        hipMemsetAsync(histe, 0, (size_t)BATCH * HIST_MAX * EMB * 4, stream);

        k_init_acc<<<(n4 + 255) / 256, 256, 0, stream>>>(embedding, gamma, acc, n4);
        long long totA = (long long)nnzA * EMB4;
        int blocksA = (int)((totA + 255) / 256);
        k_spmm_atomic<<<blocksA, 256, 0, stream>>>(adj_row, adj_col, adj_val, gamma, 1,
                                                   embedding, buf1, nnzA);
        k_acc_add<<<(n4 + 255) / 256, 256, 0, stream>>>(acc, buf1, n4);
        k_spmm_atomic<<<blocksA, 256, 0, stream>>>(adj_row, adj_col, adj_val, gamma, 2,
                                                   buf1, buf2, nnzA);
        k_acc_add<<<(n4 + 255) / 256, 256, 0, stream>>>(acc, buf2, n4);
        k_spmm_atomic<<<blocksA, 256, 0, stream>>>(adj_row, adj_col, adj_val, gamma, 3,
                                                   buf2, acc, nnzA);
    }

    // hist_emb = H @ item_embeddings (tiny, atomic scatter is fine)
    k_spmm_atomic<<<blocksH, 256, 0, stream>>>(hist_row, hist_col, hist_val, gamma, -1,
                                               acc, histe, nnzH);

    // attention head
    k_attn<<<BATCH, 128, 0, stream>>>(histe, hist_len, user, user_embedding, W1, user_out);
}

// Round 8
// 1583.713 us; speedup vs baseline: 2.2726x; 1.0948x over previous
//
#include <hip/hip_runtime.h>
#include <hip/hip_fp16.h>

#define EMB 100
#define EMB4 25            // EMB/4 float4s per row (fp32 layouts)
#define SLOTS 13           // ceil(EMB/8) slots of 8 halves per row
#define PADH 104           // padded halves per row (13*8)
#define N_ITEMS 200000
#define BATCH 100
#define HIST_MAX 50
#define ITEM_ELEMS 20000000  // N_ITEMS * EMB
#define SCAN_B 1024
#define NSCAN_BLOCKS ((N_ITEMS + SCAN_B - 1) / SCAN_B)   // 196 (< 256)
#define VALQ 16383.0f      // 14-bit val quantization (validated: absmax 0.125)

// binned-fill geometry
#define ENT 8192           // entries per binning block
#define BIN_SHIFT 10
#define ROWS_PER_BIN 1024
#define NBINS ((N_ITEMS + ROWS_PER_BIN - 1) >> BIN_SHIFT)   // 196

typedef unsigned int u32;
typedef unsigned long long u64;

// ================= CSR build =================

__global__ void k_histogram(const int* __restrict__ row, int* __restrict__ cnt, int nnz) {
    int i = blockIdx.x * blockDim.x + threadIdx.x;
    if (i < nnz) atomicAdd(&cnt[row[i]], 1);
}

// per-block inclusive scan; writes out[i+1] (pre-offset) and block sum
__global__ void k_scan_local(const int* __restrict__ cnt, int* __restrict__ rowptr,
                             int* __restrict__ blocksum, int n) {
    __shared__ int sd[SCAN_B];
    int b = blockIdx.x, tid = threadIdx.x;
    int i = b * SCAN_B + tid;
    int v = (i < n) ? cnt[i] : 0;
    sd[tid] = v;
    __syncthreads();
    for (int off = 1; off < SCAN_B; off <<= 1) {
        int t = (tid >= off) ? sd[tid - off] : 0;
        __syncthreads();
        sd[tid] += t;
        __syncthreads();
    }
    if (i < n) rowptr[i + 1] = sd[tid];
    if (tid == SCAN_B - 1) blocksum[b] = sd[tid];
}

// single block: exclusive scan of <=256 block sums in place
__global__ void k_scan_blocks(int* __restrict__ blocksum, int nb) {
    __shared__ int sd[256];
    int tid = threadIdx.x;
    int v = (tid < nb) ? blocksum[tid] : 0;
    sd[tid] = v;
    __syncthreads();
    for (int off = 1; off < 256; off <<= 1) {
        int t = (tid >= off) ? sd[tid - off] : 0;
        __syncthreads();
        sd[tid] += t;
        __syncthreads();
    }
    if (tid < nb) blocksum[tid] = sd[tid] - v;  // exclusive
}

__global__ void k_scan_add(int* __restrict__ rowptr, const int* __restrict__ blocksum, int n) {
    int i = blockIdx.x * blockDim.x + threadIdx.x;
    if (i == 0) rowptr[0] = 0;
    if (i < n) rowptr[i + 1] += blocksum[i / SCAN_B];
}

// -------- binned fill: every write coalesced or block-private-window --------
// Pass A: per-(block, bin) counts via LDS histogram. No global atomics.
__global__ __launch_bounds__(256)
void k_countbins(const int* __restrict__ row, int nnz, int nblk,
                 int* __restrict__ counts) {
    __shared__ int h[NBINS];
    int blk = blockIdx.x;
    for (int b = threadIdx.x; b < NBINS; b += 256) h[b] = 0;
    __syncthreads();
    int i0 = blk * ENT;
    int i1 = i0 + ENT; if (i1 > nnz) i1 = nnz;
    for (int i = i0 + threadIdx.x; i < i1; i += 256)
        atomicAdd(&h[row[i] >> BIN_SHIFT], 1);
    __syncthreads();
    for (int b = threadIdx.x; b < NBINS; b += 256)
        counts[b * nblk + blk] = h[b];   // bin-major layout for the scan
}

// Pass C: write each entry into its (bin, block) run at offs + LDS-rank.
// Runs are ~42x8B contiguous and written by ONE block temporally close
// -> lines fill while L2-resident -> writeback ~= payload (the r6/r7 lesson).
__global__ __launch_bounds__(256)
void k_binfill(const int* __restrict__ row, const int* __restrict__ col,
               const float* __restrict__ val, const int* __restrict__ offs,
               int nnz, int nblk, u64* __restrict__ stage) {
    __shared__ int base[NBINS];
    __shared__ int h[NBINS];
    int blk = blockIdx.x;
    for (int b = threadIdx.x; b < NBINS; b += 256) {
        base[b] = offs[b * nblk + blk];
        h[b] = 0;
    }
    __syncthreads();
    int i0 = blk * ENT;
    int i1 = i0 + ENT; if (i1 > nnz) i1 = nnz;
    for (int i = i0 + threadIdx.x; i < i1; i += 256) {
        int r = row[i];
        int b = r >> BIN_SHIFT;
        int rank = atomicAdd(&h[b], 1);
        u32 q = (u32)__float2uint_rn(val[i] * VALQ);
        u32 cv = ((u32)col[i] << 14) | q;
        stage[base[b] + rank] = ((u64)(u32)(r & (ROWS_PER_BIN - 1)) << 32) | cv;
    }
}

// Pass 2: one block per bin; coalesced stage read; LDS cursors (no global
// atomics); scattered 4B writes confined to the bin's ~131KB CSR window.
// Invariant: stage bin b's region == [rowptr[b<<10], rowptr[min((b+1)<<10,N)]).
__global__ __launch_bounds__(512)
void k_place2(const u64* __restrict__ stage, const int* __restrict__ rowptr,
              u32* __restrict__ cvp) {
    __shared__ int cur[ROWS_PER_BIN];
    int b = blockIdx.x;
    int r0 = b << BIN_SHIFT;
    int rend = r0 + ROWS_PER_BIN; if (rend > N_ITEMS) rend = N_ITEMS;
    int nr = rend - r0;
    for (int i = threadIdx.x; i < nr; i += 512) cur[i] = rowptr[r0 + i];
    __syncthreads();
    int jb = rowptr[r0], je = rowptr[rend];
    for (int j = jb + threadIdx.x; j < je; j += 512) {
        u64 e = stage[j];
        int rl = (int)(e >> 32);
        int pos = atomicAdd(&cur[rl], 1);
        cvp[pos] = (u32)e;
    }
}

// ================= fp32 -> padded fp16 row conversion =================
// dst rows: 104 halves (elements 100..103 zero-padded)
__global__ void k_to_half(const float* __restrict__ src, __half* __restrict__ dst) {
    int t = blockIdx.x * blockDim.x + threadIdx.x;
    if (t >= N_ITEMS * SLOTS) return;
    int r = t / SLOTS;
    int sl = t - r * SLOTS;
    int e0 = sl * 8;
    const float* s = src + r * EMB;
    __half h[8];
#pragma unroll
    for (int k = 0; k < 8; k++) {
        int e = e0 + k;
        h[k] = __float2half((e < EMB) ? s[e] : 0.f);
    }
    *(uint4*)(dst + r * PADH + e0) = *(const uint4*)h;
}

// ================= gather SpMM (fp16 x-table, packed 4B cvp) =================
// thread t -> (row r = t/13, 8-half slot sl = t%13). 13 lanes per row read a
// contiguous 208B row segment -> full cache-line utilization on the gather.
// acc!=null => final mode: acc = g0*emb + h1 + h2 + g[gidx]*sum  (fp32 out)
// else      => outh = fp16(g[gidx]*sum)

__device__ __forceinline__ void fma8(float s[8], const uint4& hv, float f) {
    const __half2* hp = reinterpret_cast<const __half2*>(&hv);
#pragma unroll
    for (int k = 0; k < 4; k++) {
        float2 p = __half22float2(hp[k]);
        s[2 * k]     += f * p.x;
        s[2 * k + 1] += f * p.y;
    }
}

__global__ void k_spmm_gather_h(const int* __restrict__ rowptr, const u32* __restrict__ cvp,
                                const __half* __restrict__ x,
                                const float* __restrict__ gamma, int gidx,
                                __half* __restrict__ outh,
                                const float* __restrict__ emb,
                                const __half* __restrict__ h1, const __half* __restrict__ h2,
                                float* __restrict__ acc) {
    int t = blockIdx.x * blockDim.x + threadIdx.x;
    if (t >= N_ITEMS * SLOTS) return;
    int r = t / SLOTS;
    int sl = t - r * SLOTS;
    int e0 = sl * 8;
    int j0 = rowptr[r], j1 = rowptr[r + 1];
    const float inv = 1.0f / VALQ;
    float s[8] = {0.f, 0.f, 0.f, 0.f, 0.f, 0.f, 0.f, 0.f};
    int j = j0;
    for (; j + 4 <= j1; j += 4) {
        u32 w0 = cvp[j + 0];
        u32 w1 = cvp[j + 1];
        u32 w2 = cvp[j + 2];
        u32 w3 = cvp[j + 3];
        uint4 v0 = *(const uint4*)(x + (w0 >> 14) * PADH + e0);
        uint4 v1 = *(const uint4*)(x + (w1 >> 14) * PADH + e0);
        uint4 v2 = *(const uint4*)(x + (w2 >> 14) * PADH + e0);
        uint4 v3 = *(const uint4*)(x + (w3 >> 14) * PADH + e0);
        fma8(s, v0, (float)(w0 & 16383u) * inv);
        fma8(s, v1, (float)(w1 & 16383u) * inv);
        fma8(s, v2, (float)(w2 & 16383u) * inv);
        fma8(s, v3, (float)(w3 & 16383u) * inv);
    }
    for (; j < j1; ++j) {
        u32 w = cvp[j];
        uint4 v = *(const uint4*)(x + (w >> 14) * PADH + e0);
        fma8(s, v, (float)(w & 16383u) * inv);
    }
    float g = gamma[gidx];
#pragma unroll
    for (int k = 0; k < 8; k++) s[k] *= g;

    if (acc) {
        float g0 = gamma[0];
        uint4 a = *(const uint4*)(h1 + r * PADH + e0);
        uint4 b = *(const uint4*)(h2 + r * PADH + e0);
        const __half2* ap = reinterpret_cast<const __half2*>(&a);
        const __half2* bp = reinterpret_cast<const __half2*>(&b);
        float o[8];
#pragma unroll
        for (int k = 0; k < 4; k++) {
            float2 pa = __half22float2(ap[k]);
            float2 pb = __half22float2(bp[k]);
            o[2 * k]     = s[2 * k]     + pa.x + pb.x;
            o[2 * k + 1] = s[2 * k + 1] + pa.y + pb.y;
        }
        const float* ep = emb + r * EMB + e0;
        float* op = acc + r * EMB + e0;
        float4 e1v = *(const float4*)(ep);
        float4 w1v = make_float4(o[0] + g0 * e1v.x, o[1] + g0 * e1v.y,
                                 o[2] + g0 * e1v.z, o[3] + g0 * e1v.w);
        *(float4*)(op) = w1v;
        if (e0 + 8 <= EMB) {   // last slot (e0=96) writes only 4 valid floats
            float4 e2v = *(const float4*)(ep + 4);
            float4 w2v = make_float4(o[4] + g0 * e2v.x, o[5] + g0 * e2v.y,
                                     o[6] + g0 * e2v.z, o[7] + g0 * e2v.w);
            *(float4*)(op + 4) = w2v;
        }
    } else {
        __half hh[8];
#pragma unroll
        for (int k = 0; k < 8; k++) hh[k] = __float2half(s[k]);
        *(uint4*)(outh + r * PADH + e0) = *(const uint4*)hh;
    }
}

// ================= fallback atomic path (also used for tiny hist SpMM) =================

__global__ void k_init_acc(const float* __restrict__ emb,
                           const float* __restrict__ gamma,
                           float* __restrict__ acc, int n4) {
    int t = blockIdx.x * blockDim.x + threadIdx.x;
    if (t >= n4) return;
    float g = gamma[0];
    float4 v = ((const float4*)emb)[t];
    v.x *= g; v.y *= g; v.z *= g; v.w *= g;
    ((float4*)acc)[t] = v;
}

__global__ void k_acc_add(float* __restrict__ acc,
                          const float* __restrict__ item, int n4) {
    int t = blockIdx.x * blockDim.x + threadIdx.x;
    if (t >= n4) return;
    float4 a = ((float4*)acc)[t];
    float4 b = ((const float4*)item)[t];
    a.x += b.x; a.y += b.y; a.z += b.z; a.w += b.w;
    ((float4*)acc)[t] = a;
}

__global__ void k_spmm_atomic(const int* __restrict__ row,
                              const int* __restrict__ col,
                              const float* __restrict__ val,
                              const float* __restrict__ gamma, int gidx,
                              const float* __restrict__ x,
                              float* __restrict__ out, int nnz) {
    long long t = (long long)blockIdx.x * blockDim.x + threadIdx.x;
    long long total = (long long)nnz * EMB4;
    if (t >= total) return;
    int n = (int)(t / EMB4);
    int q = (int)(t % EMB4);
    int r = row[n];
    int c = col[n];
    float s = (gidx >= 0) ? gamma[gidx] : 1.0f;
    float v = val[n] * s;
    float4 xv = ((const float4*)x)[c * EMB4 + q];
    float* o = out + (long long)r * EMB + q * 4;
    atomicAdd(o + 0, v * xv.x);
    atomicAdd(o + 1, v * xv.y);
    atomicAdd(o + 2, v * xv.z);
    atomicAdd(o + 3, v * xv.w);
}

// ================= attention head =================
__global__ void k_attn(const float* __restrict__ hist_emb,   // [B*H, EMB]
                       const int* __restrict__ hist_len,
                       const int* __restrict__ user,
                       const float* __restrict__ user_emb,   // [N_USERS, EMB]
                       const float* __restrict__ W1,         // [2*EMB]
                       float* __restrict__ out_user) {       // [B, EMB]
    __shared__ float w[2 * EMB];
    __shared__ float he[HIST_MAX * EMB];
    __shared__ float alpha[HIST_MAX];
    __shared__ float ued, mx, sm;
    int b = blockIdx.x;
    int tid = threadIdx.x;

    for (int i = tid; i < 2 * EMB; i += blockDim.x) w[i] = W1[i];
    for (int i = tid; i < HIST_MAX * EMB; i += blockDim.x)
        he[i] = hist_emb[(long long)b * HIST_MAX * EMB + i];
    __syncthreads();

    if (tid == 0) {
        const float* ue = user_emb + (long long)user[b] * EMB;
        float s = 0.f;
        for (int e = 0; e < EMB; e++) s += ue[e] * w[e];
        ued = s;
    }
    __syncthreads();

    int len = hist_len[b];
    if (tid < HIST_MAX) {
        float d = 0.f;
        for (int e = 0; e < EMB; e++) d += he[tid * EMB + e] * w[EMB + e];
        alpha[tid] = ued + d + (tid >= len ? -99999.0f : 0.0f);
    }
    __syncthreads();

    if (tid == 0) {
        float m = -1e30f;
        for (int h = 0; h < HIST_MAX; h++) m = fmaxf(m, alpha[h]);
        mx = m;
    }
    __syncthreads();
    if (tid < HIST_MAX) alpha[tid] = expf(alpha[tid] - mx);
    __syncthreads();
    if (tid == 0) {
        float s = 0.f;
        for (int h = 0; h < HIST_MAX; h++) s += alpha[h];
        sm = s;
    }
    __syncthreads();

    float denom = (len == 0) ? 1.0f : (float)len;
    if (tid < EMB) {
        float s = 0.f;
        for (int h = 0; h < HIST_MAX; h++) s += alpha[h] * he[h * EMB + tid];
        out_user[(long long)b * EMB + tid] = s / (sm * denom);
    }
}

extern "C" void kernel_launch(void* const* d_in, const int* in_sizes, int n_in,
                              void* d_out, int out_size, void* d_ws, size_t ws_size,
                              hipStream_t stream) {
    const int*   adj_row  = (const int*)d_in[0];
    const int*   adj_col  = (const int*)d_in[1];
    const float* adj_val  = (const float*)d_in[2];
    const int*   hist_row = (const int*)d_in[3];
    const int*   hist_col = (const int*)d_in[4];
    const float* hist_val = (const float*)d_in[5];
    const int*   hist_len = (const int*)d_in[6];
    const int*   user     = (const int*)d_in[7];
    const float* embedding      = (const float*)d_in[8];
    const float* user_embedding = (const float*)d_in[9];
    const float* gamma    = (const float*)d_in[10];
    const float* W1       = (const float*)d_in[11];

    float* acc      = (float*)d_out;            // item_embeddings [200000,100]
    float* user_out = acc + ITEM_ELEMS;         // [100,100]

    int nnzA = in_sizes[0];
    int nnzH = in_sizes[3];

    // binned-fill runtime geometry
    int nblk = (nnzA + ENT - 1) / ENT;           // 782 @ 6.4M
    int countsN = NBINS * nblk;                  // 153K @ 6.4M
    int nsb = (countsN + SCAN_B - 1) / SCAN_B;   // 150 (<256)

    // workspace layout
    // main path: 3 fp16 tables hb0..hb2 (41.6MB each) + 4B packed cvp.
    // stage (8B/entry) overlays hb1+hb2 (dead until gathers run).
    // fallback path overlays its two fp32 buffers on the same region.
    const size_t HBT = (size_t)N_ITEMS * PADH * sizeof(__half);  // 41,600,000
    char* ws = (char*)d_ws;
    __half* hb0 = (__half*)(ws + 0 * HBT);
    __half* hb1 = (__half*)(ws + 1 * HBT);
    __half* hb2 = (__half*)(ws + 2 * HBT);
    u64*    stage = (u64*)(ws + 1 * HBT);       // overlays hb1/hb2
    float*  buf1 = (float*)(ws + 0);            // fallback only
    float*  buf2 = (float*)(ws + 80000000ULL);  // fallback only
    size_t off = 3 * HBT;                        // 124,800,000
    u32*   cvp  = (u32*)(ws + off);       off += (size_t)nnzA * 4;        // packed CSR
    int*   rowptr = (int*)(ws + off);     off += ((size_t)N_ITEMS + 4) * 4;
    int*   cnt  = (int*)(ws + off);       off += (size_t)N_ITEMS * 4;
    int*   blocksum = (int*)(ws + off);   off += 256 * 4;
    int*   blocksum2 = (int*)(ws + off);  off += 256 * 4;
    int*   counts = (int*)(ws + off);     off += (size_t)countsN * 4;
    int*   offs = (int*)(ws + off);       off += ((size_t)countsN + 8) * 4;
    float* histe = (float*)(ws + off);    off += (size_t)BATCH * HIST_MAX * EMB * 4;
    size_t need_csr = off;
    if ((size_t)nnzA * 8 > 2 * HBT) need_csr = (size_t)1 << 62;  // stage overlay wouldn't fit
    if (nsb > 256) need_csr = (size_t)1 << 62;                   // counts scan wouldn't fit

    const int n4 = ITEM_ELEMS / 4;
    long long totH = (long long)nnzH * EMB4;
    int blocksH = (int)((totH + 255) / 256);

    if (ws_size >= need_csr) {
        // ---------- CSR (binned fill) + fp16 gather path ----------
        hipMemsetAsync(cnt, 0, (size_t)N_ITEMS * 4, stream);
        hipMemsetAsync(histe, 0, (size_t)BATCH * HIST_MAX * EMB * 4, stream);

        int bN = (nnzA + 255) / 256;
        // rowptr (per-row) scan
        k_histogram<<<bN, 256, 0, stream>>>(adj_row, cnt, nnzA);
        k_scan_local<<<NSCAN_BLOCKS, SCAN_B, 0, stream>>>(cnt, rowptr, blocksum, N_ITEMS);
        k_scan_blocks<<<1, 256, 0, stream>>>(blocksum, NSCAN_BLOCKS);
        k_scan_add<<<(N_ITEMS + 255) / 256, 256, 0, stream>>>(rowptr, blocksum, N_ITEMS);
        // per-(bin,block) counts + scan -> contention-free stage offsets
        k_countbins<<<nblk, 256, 0, stream>>>(adj_row, nnzA, nblk, counts);
        k_scan_local<<<nsb, SCAN_B, 0, stream>>>(counts, offs, blocksum2, countsN);
        k_scan_blocks<<<1, 256, 0, stream>>>(blocksum2, nsb);
        k_scan_add<<<(countsN + 255) / 256, 256, 0, stream>>>(offs, blocksum2, countsN);
        // stage (bin-grouped, coalesced-ish runs) then place (L2-window scatter)
        k_binfill<<<nblk, 256, 0, stream>>>(adj_row, adj_col, adj_val, offs, nnzA, nblk, stage);
        k_place2<<<NBINS, 512, 0, stream>>>(stage, rowptr, cvp);

        int gThreads = N_ITEMS * SLOTS;          // 2.6M
        int gBlocks = (gThreads + 255) / 256;
        // embedding -> fp16 padded table
        k_to_half<<<gBlocks, 256, 0, stream>>>(embedding, hb0);
        // layer 1: hb1 = fp16(g1 * A @ hb0)   (stage is dead from here)
        k_spmm_gather_h<<<gBlocks, 256, 0, stream>>>(rowptr, cvp, hb0, gamma, 1,
                                                     hb1, nullptr, nullptr, nullptr, nullptr);
        // layer 2: hb2 = fp16(g2 * A @ hb1)
        k_spmm_gather_h<<<gBlocks, 256, 0, stream>>>(rowptr, cvp, hb1, gamma, 2,
                                                     hb2, nullptr, nullptr, nullptr, nullptr);
        // layer 3 + fused epilogue: acc = g0*emb + hb1 + hb2 + g3 * A @ hb2   (fp32 out)
        k_spmm_gather_h<<<gBlocks, 256, 0, stream>>>(rowptr, cvp, hb2, gamma, 3,
                                                     nullptr, embedding, hb1, hb2, acc);
    } else {
        // ---------- fallback atomic path (fp32 throughout) ----------
        hipMemsetAsync(buf1, 0, 80000000ULL, stream);
        hipMemsetAsync(buf2, 0, 80000000ULL, stream);
        hipMemsetAsync(histe, 0, (size_t)BATCH * HIST_MAX * EMB * 4, stream);

        k_init_acc<<<(n4 + 255) / 256, 256, 0, stream>>>(embedding, gamma, acc, n4);
        long long totA = (long long)nnzA * EMB4;
        int blocksA = (int)((totA + 255) / 256);
        k_spmm_atomic<<<blocksA, 256, 0, stream>>>(adj_row, adj_col, adj_val, gamma, 1,
                                                   embedding, buf1, nnzA);
        k_acc_add<<<(n4 + 255) / 256, 256, 0, stream>>>(acc, buf1, n4);
        k_spmm_atomic<<<blocksA, 256, 0, stream>>>(adj_row, adj_col, adj_val, gamma, 2,
                                                   buf1, buf2, nnzA);
        k_acc_add<<<(n4 + 255) / 256, 256, 0, stream>>>(acc, buf2, n4);
        k_spmm_atomic<<<blocksA, 256, 0, stream>>>(adj_row, adj_col, adj_val, gamma, 3,
                                                   buf2, acc, nnzA);
    }

    // hist_emb = H @ item_embeddings (tiny, atomic scatter is fine)
    k_spmm_atomic<<<blocksH, 256, 0, stream>>>(hist_row, hist_col, hist_val, gamma, -1,
                                               acc, histe, nnzH);

    // attention head
    k_attn<<<BATCH, 128, 0, stream>>>(histe, hist_len, user, user_embedding, W1, user_out);
}

// Round 9
// 1542.110 us; speedup vs baseline: 2.3339x; 1.0270x over previous
//
#include <hip/hip_runtime.h>
#include <hip/hip_fp16.h>

#define EMB 100
#define EMB4 25            // EMB/4 float4s per row (fp32 layouts)
#define SLOTS 13           // ceil(EMB/8) slots of 8 halves per row
#define PADH 104           // padded halves per row (13*8)
#define N_ITEMS 200000
#define BATCH 100
#define HIST_MAX 50
#define ITEM_ELEMS 20000000  // N_ITEMS * EMB
#define SCAN_B 1024
#define NSCAN_BLOCKS ((N_ITEMS + SCAN_B - 1) / SCAN_B)   // 196 (< 256)
#define VALQ 16383.0f      // 14-bit val quantization (validated: absmax 0.125)

// binned-fill geometry
#define ENT 8192           // entries per binning block
#define BIN_SHIFT 10
#define ROWS_PER_BIN 1024
#define NBINS ((N_ITEMS + ROWS_PER_BIN - 1) >> BIN_SHIFT)   // 196

typedef unsigned int u32;
typedef unsigned long long u64;

// ================= fused prep: row histogram + bin counts + emb->fp16 =================
// blocks [0, nblk): per-row global histogram (200K addrs, 32/addr - proven) +
//                   per-(bin,block) LDS counts (r8-proven).
// blocks [nblk, ...): embedding -> padded fp16 table hb0.
__global__ __launch_bounds__(256)
void k_prep(const int* __restrict__ row, int nnz, int nblk,
            int* __restrict__ cnt, int* __restrict__ counts,
            const float* __restrict__ emb_src, __half* __restrict__ hb0) {
    int blk = blockIdx.x;
    if (blk < nblk) {
        __shared__ int h[NBINS];
        for (int b = threadIdx.x; b < NBINS; b += 256) h[b] = 0;
        __syncthreads();
        int i0 = blk * ENT;
        int i1 = i0 + ENT; if (i1 > nnz) i1 = nnz;
        for (int i = i0 + threadIdx.x; i < i1; i += 256) {
            int r = row[i];
            atomicAdd(&cnt[r], 1);
            atomicAdd(&h[r >> BIN_SHIFT], 1);
        }
        __syncthreads();
        for (int b = threadIdx.x; b < NBINS; b += 256)
            counts[b * nblk + blk] = h[b];   // bin-major for the scan
    } else {
        int t = (blk - nblk) * 256 + threadIdx.x;
        if (t >= N_ITEMS * SLOTS) return;
        int r = t / SLOTS;
        int sl = t - r * SLOTS;
        int e0 = sl * 8;
        const float* s = emb_src + r * EMB;
        __half hh[8];
#pragma unroll
        for (int k = 0; k < 8; k++) {
            int e = e0 + k;
            hh[k] = __float2half((e < EMB) ? s[e] : 0.f);
        }
        *(uint4*)(hb0 + r * PADH + e0) = *(const uint4*)hh;
    }
}

// ================= dual scans (rowptr chain + counts chain in one launch) =================

__global__ void k_scan_dual(const int* __restrict__ a, int* __restrict__ outa,
                            int* __restrict__ bsuma, int na, int nba,
                            const int* __restrict__ b, int* __restrict__ outb,
                            int* __restrict__ bsumb, int nb) {
    __shared__ int sd[SCAN_B];
    int blk = blockIdx.x, tid = threadIdx.x;
    const int* src; int* out; int* bsum; int n; int lb;
    if (blk < nba) { src = a; out = outa; bsum = bsuma; n = na; lb = blk; }
    else           { src = b; out = outb; bsum = bsumb; n = nb; lb = blk - nba; }
    int i = lb * SCAN_B + tid;
    int v = (i < n) ? src[i] : 0;
    sd[tid] = v;
    __syncthreads();
    for (int off = 1; off < SCAN_B; off <<= 1) {
        int t = (tid >= off) ? sd[tid - off] : 0;
        __syncthreads();
        sd[tid] += t;
        __syncthreads();
    }
    if (i < n) out[i + 1] = sd[tid];
    if (tid == SCAN_B - 1) bsum[lb] = sd[tid];
}

// single block: exclusive-scan both blocksum arrays sequentially (each <=256)
__global__ void k_scan_blocks_dual(int* __restrict__ ba, int nba,
                                   int* __restrict__ bb, int nbb) {
    __shared__ int sd[256];
    int tid = threadIdx.x;
    // pass 1: ba
    int v = (tid < nba) ? ba[tid] : 0;
    sd[tid] = v;
    __syncthreads();
    for (int off = 1; off < 256; off <<= 1) {
        int t = (tid >= off) ? sd[tid - off] : 0;
        __syncthreads();
        sd[tid] += t;
        __syncthreads();
    }
    if (tid < nba) ba[tid] = sd[tid] - v;
    __syncthreads();
    // pass 2: bb
    v = (tid < nbb) ? bb[tid] : 0;
    sd[tid] = v;
    __syncthreads();
    for (int off = 1; off < 256; off <<= 1) {
        int t = (tid >= off) ? sd[tid - off] : 0;
        __syncthreads();
        sd[tid] += t;
        __syncthreads();
    }
    if (tid < nbb) bb[tid] = sd[tid] - v;
}

__global__ void k_scan_add_dual(int* __restrict__ outa, const int* __restrict__ ba,
                                int na, int nblka,
                                int* __restrict__ outb, const int* __restrict__ bb,
                                int nb) {
    int blk = blockIdx.x;
    if (blk < nblka) {
        int i = blk * 256 + threadIdx.x;
        if (i == 0) outa[0] = 0;
        if (i < na) outa[i + 1] += ba[i / SCAN_B];
    } else {
        int i = (blk - nblka) * 256 + threadIdx.x;
        if (i == 0) outb[0] = 0;
        if (i < nb) outb[i + 1] += bb[i / SCAN_B];
    }
}

// -------- binned fill (r8-proven): block-private runs then L2-window place --------
__global__ __launch_bounds__(256)
void k_binfill(const int* __restrict__ row, const int* __restrict__ col,
               const float* __restrict__ val, const int* __restrict__ offs,
               int nnz, int nblk, u64* __restrict__ stage) {
    __shared__ int base[NBINS];
    __shared__ int h[NBINS];
    int blk = blockIdx.x;
    for (int b = threadIdx.x; b < NBINS; b += 256) {
        base[b] = offs[b * nblk + blk];
        h[b] = 0;
    }
    __syncthreads();
    int i0 = blk * ENT;
    int i1 = i0 + ENT; if (i1 > nnz) i1 = nnz;
    for (int i = i0 + threadIdx.x; i < i1; i += 256) {
        int r = row[i];
        int b = r >> BIN_SHIFT;
        int rank = atomicAdd(&h[b], 1);
        u32 q = (u32)__float2uint_rn(val[i] * VALQ);
        u32 cv = ((u32)col[i] << 14) | q;
        stage[base[b] + rank] = ((u64)(u32)(r & (ROWS_PER_BIN - 1)) << 32) | cv;
    }
}

__global__ __launch_bounds__(512)
void k_place2(const u64* __restrict__ stage, const int* __restrict__ rowptr,
              u32* __restrict__ cvp) {
    __shared__ int cur[ROWS_PER_BIN];
    int b = blockIdx.x;
    int r0 = b << BIN_SHIFT;
    int rend = r0 + ROWS_PER_BIN; if (rend > N_ITEMS) rend = N_ITEMS;
    int nr = rend - r0;
    for (int i = threadIdx.x; i < nr; i += 512) cur[i] = rowptr[r0 + i];
    __syncthreads();
    int jb = rowptr[r0], je = rowptr[rend];
    for (int j = jb + threadIdx.x; j < je; j += 512) {
        u64 e = stage[j];
        int rl = (int)(e >> 32);
        int pos = atomicAdd(&cur[rl], 1);
        cvp[pos] = (u32)e;
    }
}

// ================= gather SpMM (fp16 x-table, packed 4B cvp) =================
// thread t -> (row r = t/13, 8-half slot sl = t%13). 13 lanes per row read a
// contiguous 208B row segment -> full cache-line utilization on the gather.
// acc!=null => final mode: acc = g0*embh + h1 + h2 + g[gidx]*sum  (fp32 out)
// else      => outh = fp16(g[gidx]*sum)

__device__ __forceinline__ void fma8(float s[8], const uint4& hv, float f) {
    const __half2* hp = reinterpret_cast<const __half2*>(&hv);
#pragma unroll
    for (int k = 0; k < 4; k++) {
        float2 p = __half22float2(hp[k]);
        s[2 * k]     += f * p.x;
        s[2 * k + 1] += f * p.y;
    }
}

__global__ void k_spmm_gather_h(const int* __restrict__ rowptr, const u32* __restrict__ cvp,
                                const __half* __restrict__ x,
                                const float* __restrict__ gamma, int gidx,
                                __half* __restrict__ outh,
                                const __half* __restrict__ embh,
                                const __half* __restrict__ h1, const __half* __restrict__ h2,
                                float* __restrict__ acc) {
    int t = blockIdx.x * blockDim.x + threadIdx.x;
    if (t >= N_ITEMS * SLOTS) return;
    int r = t / SLOTS;
    int sl = t - r * SLOTS;
    int e0 = sl * 8;
    int j0 = rowptr[r], j1 = rowptr[r + 1];
    const float inv = 1.0f / VALQ;
    float s[8] = {0.f, 0.f, 0.f, 0.f, 0.f, 0.f, 0.f, 0.f};
    int j = j0;
    for (; j + 4 <= j1; j += 4) {
        u32 w0 = cvp[j + 0];
        u32 w1 = cvp[j + 1];
        u32 w2 = cvp[j + 2];
        u32 w3 = cvp[j + 3];
        uint4 v0 = *(const uint4*)(x + (w0 >> 14) * PADH + e0);
        uint4 v1 = *(const uint4*)(x + (w1 >> 14) * PADH + e0);
        uint4 v2 = *(const uint4*)(x + (w2 >> 14) * PADH + e0);
        uint4 v3 = *(const uint4*)(x + (w3 >> 14) * PADH + e0);
        fma8(s, v0, (float)(w0 & 16383u) * inv);
        fma8(s, v1, (float)(w1 & 16383u) * inv);
        fma8(s, v2, (float)(w2 & 16383u) * inv);
        fma8(s, v3, (float)(w3 & 16383u) * inv);
    }
    for (; j < j1; ++j) {
        u32 w = cvp[j];
        uint4 v = *(const uint4*)(x + (w >> 14) * PADH + e0);
        fma8(s, v, (float)(w & 16383u) * inv);
    }
    float g = gamma[gidx];
#pragma unroll
    for (int k = 0; k < 8; k++) s[k] *= g;

    if (acc) {
        float g0 = gamma[0];
        uint4 a = *(const uint4*)(h1 + r * PADH + e0);
        uint4 b = *(const uint4*)(h2 + r * PADH + e0);
        uint4 e = *(const uint4*)(embh + r * PADH + e0);
        const __half2* ap = reinterpret_cast<const __half2*>(&a);
        const __half2* bp = reinterpret_cast<const __half2*>(&b);
        const __half2* ep = reinterpret_cast<const __half2*>(&e);
        float o[8];
#pragma unroll
        for (int k = 0; k < 4; k++) {
            float2 pa = __half22float2(ap[k]);
            float2 pb = __half22float2(bp[k]);
            float2 pe = __half22float2(ep[k]);
            o[2 * k]     = s[2 * k]     + pa.x + pb.x + g0 * pe.x;
            o[2 * k + 1] = s[2 * k + 1] + pa.y + pb.y + g0 * pe.y;
        }
        float* op = acc + r * EMB + e0;
        *(float4*)(op) = make_float4(o[0], o[1], o[2], o[3]);
        if (e0 + 8 <= EMB)   // last slot (e0=96) writes only 4 valid floats
            *(float4*)(op + 4) = make_float4(o[4], o[5], o[6], o[7]);
    } else {
        __half hh[8];
#pragma unroll
        for (int k = 0; k < 8; k++) hh[k] = __float2half(s[k]);
        *(uint4*)(outh + r * PADH + e0) = *(const uint4*)hh;
    }
}

// ================= fallback atomic path (also used for tiny hist SpMM) =================

__global__ void k_init_acc(const float* __restrict__ emb,
                           const float* __restrict__ gamma,
                           float* __restrict__ acc, int n4) {
    int t = blockIdx.x * blockDim.x + threadIdx.x;
    if (t >= n4) return;
    float g = gamma[0];
    float4 v = ((const float4*)emb)[t];
    v.x *= g; v.y *= g; v.z *= g; v.w *= g;
    ((float4*)acc)[t] = v;
}

__global__ void k_acc_add(float* __restrict__ acc,
                          const float* __restrict__ item, int n4) {
    int t = blockIdx.x * blockDim.x + threadIdx.x;
    if (t >= n4) return;
    float4 a = ((float4*)acc)[t];
    float4 b = ((const float4*)item)[t];
    a.x += b.x; a.y += b.y; a.z += b.z; a.w += b.w;
    ((float4*)acc)[t] = a;
}

__global__ void k_spmm_atomic(const int* __restrict__ row,
                              const int* __restrict__ col,
                              const float* __restrict__ val,
                              const float* __restrict__ gamma, int gidx,
                              const float* __restrict__ x,
                              float* __restrict__ out, int nnz) {
    long long t = (long long)blockIdx.x * blockDim.x + threadIdx.x;
    long long total = (long long)nnz * EMB4;
    if (t >= total) return;
    int n = (int)(t / EMB4);
    int q = (int)(t % EMB4);
    int r = row[n];
    int c = col[n];
    float s = (gidx >= 0) ? gamma[gidx] : 1.0f;
    float v = val[n] * s;
    float4 xv = ((const float4*)x)[c * EMB4 + q];
    float* o = out + (long long)r * EMB + q * 4;
    atomicAdd(o + 0, v * xv.x);
    atomicAdd(o + 1, v * xv.y);
    atomicAdd(o + 2, v * xv.z);
    atomicAdd(o + 3, v * xv.w);
}

// ================= attention head =================
__global__ void k_attn(const float* __restrict__ hist_emb,   // [B*H, EMB]
                       const int* __restrict__ hist_len,
                       const int* __restrict__ user,
                       const float* __restrict__ user_emb,   // [N_USERS, EMB]
                       const float* __restrict__ W1,         // [2*EMB]
                       float* __restrict__ out_user) {       // [B, EMB]
    __shared__ float w[2 * EMB];
    __shared__ float he[HIST_MAX * EMB];
    __shared__ float alpha[HIST_MAX];
    __shared__ float ued, mx, sm;
    int b = blockIdx.x;
    int tid = threadIdx.x;

    for (int i = tid; i < 2 * EMB; i += blockDim.x) w[i] = W1[i];
    for (int i = tid; i < HIST_MAX * EMB; i += blockDim.x)
        he[i] = hist_emb[(long long)b * HIST_MAX * EMB + i];
    __syncthreads();

    if (tid == 0) {
        const float* ue = user_emb + (long long)user[b] * EMB;
        float s = 0.f;
        for (int e = 0; e < EMB; e++) s += ue[e] * w[e];
        ued = s;
    }
    __syncthreads();

    int len = hist_len[b];
    if (tid < HIST_MAX) {
        float d = 0.f;
        for (int e = 0; e < EMB; e++) d += he[tid * EMB + e] * w[EMB + e];
        alpha[tid] = ued + d + (tid >= len ? -99999.0f : 0.0f);
    }
    __syncthreads();

    if (tid == 0) {
        float m = -1e30f;
        for (int h = 0; h < HIST_MAX; h++) m = fmaxf(m, alpha[h]);
        mx = m;
    }
    __syncthreads();
    if (tid < HIST_MAX) alpha[tid] = expf(alpha[tid] - mx);
    __syncthreads();
    if (tid == 0) {
        float s = 0.f;
        for (int h = 0; h < HIST_MAX; h++) s += alpha[h];
        sm = s;
    }
    __syncthreads();

    float denom = (len == 0) ? 1.0f : (float)len;
    if (tid < EMB) {
        float s = 0.f;
        for (int h = 0; h < HIST_MAX; h++) s += alpha[h] * he[h * EMB + tid];
        out_user[(long long)b * EMB + tid] = s / (sm * denom);
    }
}

extern "C" void kernel_launch(void* const* d_in, const int* in_sizes, int n_in,
                              void* d_out, int out_size, void* d_ws, size_t ws_size,
                              hipStream_t stream) {
    const int*   adj_row  = (const int*)d_in[0];
    const int*   adj_col  = (const int*)d_in[1];
    const float* adj_val  = (const float*)d_in[2];
    const int*   hist_row = (const int*)d_in[3];
    const int*   hist_col = (const int*)d_in[4];
    const float* hist_val = (const float*)d_in[5];
    const int*   hist_len = (const int*)d_in[6];
    const int*   user     = (const int*)d_in[7];
    const float* embedding      = (const float*)d_in[8];
    const float* user_embedding = (const float*)d_in[9];
    const float* gamma    = (const float*)d_in[10];
    const float* W1       = (const float*)d_in[11];

    float* acc      = (float*)d_out;            // item_embeddings [200000,100]
    float* user_out = acc + ITEM_ELEMS;         // [100,100]

    int nnzA = in_sizes[0];
    int nnzH = in_sizes[3];

    // binned-fill runtime geometry
    int nblk = (nnzA + ENT - 1) / ENT;           // 782 @ 6.4M
    int countsN = NBINS * nblk;                  // 153K @ 6.4M
    int nsb = (countsN + SCAN_B - 1) / SCAN_B;   // 150 (<256)

    // workspace layout (identical to r8)
    const size_t HBT = (size_t)N_ITEMS * PADH * sizeof(__half);  // 41,600,000
    char* ws = (char*)d_ws;
    __half* hb0 = (__half*)(ws + 0 * HBT);
    __half* hb1 = (__half*)(ws + 1 * HBT);
    __half* hb2 = (__half*)(ws + 2 * HBT);
    u64*    stage = (u64*)(ws + 1 * HBT);       // overlays hb1/hb2
    float*  buf1 = (float*)(ws + 0);            // fallback only
    float*  buf2 = (float*)(ws + 80000000ULL);  // fallback only
    size_t off = 3 * HBT;                        // 124,800,000
    u32*   cvp  = (u32*)(ws + off);       off += (size_t)nnzA * 4;        // packed CSR
    int*   rowptr = (int*)(ws + off);     off += ((size_t)N_ITEMS + 4) * 4;
    int*   cnt  = (int*)(ws + off);       off += (size_t)N_ITEMS * 4;
    int*   blocksum = (int*)(ws + off);   off += 256 * 4;
    int*   blocksum2 = (int*)(ws + off);  off += 256 * 4;
    int*   counts = (int*)(ws + off);     off += (size_t)countsN * 4;
    int*   offs = (int*)(ws + off);       off += ((size_t)countsN + 8) * 4;
    float* histe = (float*)(ws + off);    off += (size_t)BATCH * HIST_MAX * EMB * 4;
    size_t need_csr = off;
    if ((size_t)nnzA * 8 > 2 * HBT) need_csr = (size_t)1 << 62;  // stage overlay wouldn't fit
    if (nsb > 256) need_csr = (size_t)1 << 62;                   // counts scan wouldn't fit

    const int n4 = ITEM_ELEMS / 4;
    long long totH = (long long)nnzH * EMB4;
    int blocksH = (int)((totH + 255) / 256);

    if (ws_size >= need_csr) {
        // ---------- CSR (binned fill) + fp16 gather path ----------
        hipMemsetAsync(cnt, 0, (size_t)N_ITEMS * 4, stream);
        hipMemsetAsync(histe, 0, (size_t)BATCH * HIST_MAX * EMB * 4, stream);

        int gThreads = N_ITEMS * SLOTS;          // 2.6M
        int gBlocks = (gThreads + 255) / 256;    // 10157

        // fused prep: histogram + bin counts + emb->fp16
        k_prep<<<nblk + gBlocks, 256, 0, stream>>>(adj_row, nnzA, nblk,
                                                   cnt, counts, embedding, hb0);
        // dual scans: cnt->rowptr and counts->offs
        k_scan_dual<<<NSCAN_BLOCKS + nsb, SCAN_B, 0, stream>>>(
            cnt, rowptr, blocksum, N_ITEMS, NSCAN_BLOCKS,
            counts, offs, blocksum2, countsN);
        k_scan_blocks_dual<<<1, 256, 0, stream>>>(blocksum, NSCAN_BLOCKS, blocksum2, nsb);
        int nba = (N_ITEMS + 255) / 256;
        int nbb = (countsN + 255) / 256;
        k_scan_add_dual<<<nba + nbb, 256, 0, stream>>>(rowptr, blocksum, N_ITEMS, nba,
                                                       offs, blocksum2, countsN);
        // stage (block-private runs) then place (L2-window scatter)
        k_binfill<<<nblk, 256, 0, stream>>>(adj_row, adj_col, adj_val, offs, nnzA, nblk, stage);
        k_place2<<<NBINS, 512, 0, stream>>>(stage, rowptr, cvp);

        // layer 1: hb1 = fp16(g1 * A @ hb0)   (stage is dead from here)
        k_spmm_gather_h<<<gBlocks, 256, 0, stream>>>(rowptr, cvp, hb0, gamma, 1,
                                                     hb1, nullptr, nullptr, nullptr, nullptr);
        // layer 2: hb2 = fp16(g2 * A @ hb1)
        k_spmm_gather_h<<<gBlocks, 256, 0, stream>>>(rowptr, cvp, hb1, gamma, 2,
                                                     hb2, nullptr, nullptr, nullptr, nullptr);
        // layer 3 + fused epilogue: acc = g0*hb0 + hb1 + hb2 + g3 * A @ hb2   (fp32 out)
        k_spmm_gather_h<<<gBlocks, 256, 0, stream>>>(rowptr, cvp, hb2, gamma, 3,
                                                     nullptr, hb0, hb1, hb2, acc);
    } else {
        // ---------- fallback atomic path (fp32 throughout) ----------
        hipMemsetAsync(buf1, 0, 80000000ULL, stream);
        hipMemsetAsync(buf2, 0, 80000000ULL, stream);
        hipMemsetAsync(histe, 0, (size_t)BATCH * HIST_MAX * EMB * 4, stream);

        k_init_acc<<<(n4 + 255) / 256, 256, 0, stream>>>(embedding, gamma, acc, n4);
        long long totA = (long long)nnzA * EMB4;
        int blocksA = (int)((totA + 255) / 256);
        k_spmm_atomic<<<blocksA, 256, 0, stream>>>(adj_row, adj_col, adj_val, gamma, 1,
                                                   embedding, buf1, nnzA);
        k_acc_add<<<(n4 + 255) / 256, 256, 0, stream>>>(acc, buf1, n4);
        k_spmm_atomic<<<blocksA, 256, 0, stream>>>(adj_row, adj_col, adj_val, gamma, 2,
                                                   buf1, buf2, nnzA);
        k_acc_add<<<(n4 + 255) / 256, 256, 0, stream>>>(acc, buf2, n4);
        k_spmm_atomic<<<blocksA, 256, 0, stream>>>(adj_row, adj_col, adj_val, gamma, 3,
                                                   buf2, acc, nnzA);
    }

    // hist_emb = H @ item_embeddings (tiny, atomic scatter is fine)
    k_spmm_atomic<<<blocksH, 256, 0, stream>>>(hist_row, hist_col, hist_val, gamma, -1,
                                               acc, histe, nnzH);

    // attention head
    k_attn<<<BATCH, 128, 0, stream>>>(histe, hist_len, user, user_embedding, W1, user_out);
}